// Round 1
// baseline (339.748 us; speedup 1.0000x reference)
//
#include <hip/hip_runtime.h>

// Mamba2D: B=4, C=128, H=W=64 (L=4096), D_INNER=256, D_STATE=16, DT_RANK=8, D_CONV=4
// Pipeline (fp32 throughout; threshold 0.53 absolute gives lots of headroom):
//  prep:    W2 = in_proj_w @ proj_w (512x128);  wT = x_proj_w^T (256x40);  Aneg = -exp(A_log)
//  gemm_xz: xz[b,l,o] = sum_c W2[o,c] * x[b,c,l]        (M=16384,N=512,K=128)
//  conv:    xc = silu(causal depthwise conv4(xz[...,:256]) + conv_b)
//  xdbl:    x_dbl[b,l,0:40] = xc @ x_proj_w^T            (skinny GEMM)
//  delta:   delta = softplus(x_dbl[:, :8] @ dt_proj_w^T + dt_proj_b)
//  scan:    3-phase chunked linear recurrence (32 chunks x 128 steps), phase3 fuses
//           y2 = (y_scan + xc*D) * silu(zg)
//  gemm_out: out[b,c,l] = sum_d Wout[c,d]*y2[b,l,d] + x[b,c,l]

#define LTOT 4096
#define NPAIR 1024   // b * d_inner
#define NCHUNK 32
#define CLEN 128

// ---------------- prep ----------------
__global__ void prep_kernel(const float* __restrict__ proj_w,
                            const float* __restrict__ in_proj_w,
                            const float* __restrict__ x_proj_w,
                            const float* __restrict__ A_log,
                            float* __restrict__ W2,
                            float* __restrict__ wT,
                            float* __restrict__ Aneg) {
  int idx = blockIdx.x * blockDim.x + threadIdx.x;
  if (idx < 512 * 128) {
    int o = idx >> 7, c = idx & 127;
    float acc = 0.f;
    #pragma unroll 4
    for (int i = 0; i < 128; ++i)
      acc += in_proj_w[o * 128 + i] * proj_w[i * 128 + c];
    W2[idx] = acc;
  } else if (idx < 512 * 128 + 256 * 40) {
    int t = idx - 512 * 128;
    int k = t / 40, j = t % 40;
    wT[t] = x_proj_w[j * 256 + k];
  } else if (idx < 512 * 128 + 256 * 40 + 256 * 16) {
    int t = idx - (512 * 128 + 256 * 40);
    Aneg[t] = -__expf(A_log[t]);
  }
}

// ---------------- xz GEMM: 128x128 tile, 8x8 register tile ----------------
__global__ __launch_bounds__(256) void gemm_xz_kernel(
    const float* __restrict__ x, const float* __restrict__ W2,
    float* __restrict__ xz) {
  __shared__ __align__(16) float xs[64][132];
  __shared__ __align__(16) float ws[64][132];
  int mt = blockIdx.x >> 2;      // 128 m-tiles
  int nt = blockIdx.x & 3;       // 4 o-tiles
  int m0 = mt * 128;
  int b  = m0 >> 12;
  int l0 = m0 & 4095;
  int o0 = nt * 128;
  int tid = threadIdx.x;
  int tx = tid & 15, ty = tid >> 4;
  float acc[8][8] = {};
  for (int kc = 0; kc < 128; kc += 64) {
    // x tile: xs[kk][ml] = x[b, kc+kk, l0+ml]  (direct, rows contiguous)
    #pragma unroll
    for (int j = 0; j < 8; ++j) {
      int i = tid + j * 256;
      int kk = i >> 5, colq = (i & 31) << 2;
      float4 v = *reinterpret_cast<const float4*>(
          &x[((size_t)(b * 128 + kc + kk)) * 4096 + l0 + colq]);
      *reinterpret_cast<float4*>(&xs[kk][colq]) = v;
    }
    // W tile transposed: ws[kk][o] = W2[o0+o][kc+kk]
    #pragma unroll
    for (int j = 0; j < 8; ++j) {
      int i = tid + j * 256;
      int o = i >> 4, kq = (i & 15) << 2;
      float4 v = *reinterpret_cast<const float4*>(&W2[(o0 + o) * 128 + kc + kq]);
      ws[kq + 0][o] = v.x; ws[kq + 1][o] = v.y;
      ws[kq + 2][o] = v.z; ws[kq + 3][o] = v.w;
    }
    __syncthreads();
    for (int kk = 0; kk < 64; ++kk) {
      float4 xa = *reinterpret_cast<const float4*>(&xs[kk][tx * 8]);
      float4 xb = *reinterpret_cast<const float4*>(&xs[kk][tx * 8 + 4]);
      float4 wa = *reinterpret_cast<const float4*>(&ws[kk][ty * 8]);
      float4 wb = *reinterpret_cast<const float4*>(&ws[kk][ty * 8 + 4]);
      float xv[8] = {xa.x, xa.y, xa.z, xa.w, xb.x, xb.y, xb.z, xb.w};
      float wv[8] = {wa.x, wa.y, wa.z, wa.w, wb.x, wb.y, wb.z, wb.w};
      #pragma unroll
      for (int i2 = 0; i2 < 8; ++i2)
        #pragma unroll
        for (int j2 = 0; j2 < 8; ++j2)
          acc[i2][j2] += xv[i2] * wv[j2];
    }
    __syncthreads();
  }
  #pragma unroll
  for (int i2 = 0; i2 < 8; ++i2) {
    size_t row = (size_t)(m0 + tx * 8 + i2) * 512 + o0 + ty * 8;
    float4 a{acc[i2][0], acc[i2][1], acc[i2][2], acc[i2][3]};
    float4 bq{acc[i2][4], acc[i2][5], acc[i2][6], acc[i2][7]};
    *reinterpret_cast<float4*>(&xz[row]) = a;
    *reinterpret_cast<float4*>(&xz[row + 4]) = bq;
  }
}

// ---------------- causal depthwise conv4 + silu ----------------
__global__ void conv_silu_kernel(const float* __restrict__ xz,
                                 const float* __restrict__ conv_w,
                                 const float* __restrict__ conv_b,
                                 float* __restrict__ xc) {
  int bl = blockIdx.x;        // flattened (b,l), 0..16383
  int l = bl & 4095;
  int d = threadIdx.x;        // 0..255
  float acc = conv_b[d];
  #pragma unroll
  for (int k = 0; k < 4; ++k) {
    int ls = l - 3 + k;
    if (ls >= 0)
      acc += conv_w[d * 4 + k] * xz[((size_t)(bl - 3 + k)) * 512 + d];
  }
  float s = acc * (1.f / (1.f + __expf(-acc)));
  xc[(size_t)bl * 256 + d] = s;
}

// ---------------- skinny GEMM: x_dbl (N=40, K=256) ----------------
__global__ __launch_bounds__(256) void xdbl_kernel(
    const float* __restrict__ xc, const float* __restrict__ wT,
    float* __restrict__ xdbl) {
  __shared__ __align__(16) float lx[32][256];
  int m0 = blockIdx.x * 32;
  int tid = threadIdx.x;
  #pragma unroll
  for (int jj = 0; jj < 8; ++jj) {
    int i = tid + jj * 256;
    int row = i >> 6, colq = (i & 63) << 2;
    *reinterpret_cast<float4*>(&lx[row][colq]) =
        *reinterpret_cast<const float4*>(&xc[(size_t)(m0 + row) * 256 + colq]);
  }
  __syncthreads();
  int j = tid & 63, g = tid >> 6;
  bool act = j < 40;
  float acc[8] = {};
  for (int k = 0; k < 256; ++k) {
    float w = act ? wT[k * 40 + j] : 0.f;
    #pragma unroll
    for (int i = 0; i < 8; ++i)
      acc[i] += lx[g * 8 + i][k] * w;
  }
  if (act) {
    #pragma unroll
    for (int i = 0; i < 8; ++i)
      xdbl[(size_t)(m0 + g * 8 + i) * 40 + j] = acc[i];
  }
}

// ---------------- delta = softplus(dt_r @ dt_proj_w^T + b) ----------------
__global__ void delta_kernel(const float* __restrict__ xdbl,
                             const float* __restrict__ dt_proj_w,
                             const float* __restrict__ dt_proj_b,
                             float* __restrict__ dlt) {
  int bl = blockIdx.x;
  int d = threadIdx.x;
  const float* xd = &xdbl[(size_t)bl * 40];
  float acc = dt_proj_b[d];
  #pragma unroll
  for (int r = 0; r < 8; ++r)
    acc += xd[r] * dt_proj_w[d * 8 + r];
  float sp = fmaxf(acc, 0.f) + __logf(1.f + __expf(-fabsf(acc)));
  dlt[(size_t)bl * 256 + d] = sp;
}

// ---------------- scan phase 1: per-chunk (prod dA, local h) ----------------
__global__ __launch_bounds__(256) void scan1_kernel(
    const float* __restrict__ dlt, const float* __restrict__ xc,
    const float* __restrict__ xdbl, const float* __restrict__ Aneg,
    float* __restrict__ chA, float* __restrict__ chH) {
  int wid = (blockIdx.x << 2) + (threadIdx.x >> 6);   // 0..8191
  int lane = threadIdx.x & 63;
  int c = wid & (NCHUNK - 1);
  int pg = wid >> 5;
  int g = lane >> 4, n = lane & 15;
  int p = (pg << 2) + g;          // 0..1023  (b,d) pair
  int b = p >> 8, d = p & 255;
  float An = Aneg[d * 16 + n];
  float a = 1.f, h = 0.f;
  int bl0 = b * 4096 + c * CLEN;
  for (int tt = 0; tt < CLEN; ++tt) {
    size_t bl = bl0 + tt;
    float dl = dlt[bl * 256 + d];
    float xv = xc[bl * 256 + d];
    float Bv = xdbl[bl * 40 + 8 + n];
    float dA = __expf(dl * An);
    h = dA * h + (dl * xv) * Bv;
    a *= dA;
  }
  int idx = ((c << 10) + p) * 16 + n;
  chA[idx] = a;
  chH[idx] = h;
}

// ---------------- scan phase 2: exclusive prefix over chunks ----------------
__global__ void scan2_kernel(const float* __restrict__ chA,
                             const float* __restrict__ chH,
                             float* __restrict__ h0b) {
  int q = blockIdx.x * blockDim.x + threadIdx.x;  // 0..16383
  int p = q >> 4, n = q & 15;
  float h = 0.f;
  for (int c = 0; c < NCHUNK; ++c) {
    int idx = ((c << 10) + p) * 16 + n;
    h0b[idx] = h;
    h = chA[idx] * h + chH[idx];
  }
}

// ---------------- scan phase 3: replay + y, fused epilogue ----------------
__global__ __launch_bounds__(256) void scan3_kernel(
    const float* __restrict__ dlt, const float* __restrict__ xc,
    const float* __restrict__ xdbl, const float* __restrict__ Aneg,
    const float* __restrict__ h0b, const float* __restrict__ Dvec,
    const float* __restrict__ xz, float* __restrict__ y2) {
  int wid = (blockIdx.x << 2) + (threadIdx.x >> 6);
  int lane = threadIdx.x & 63;
  int c = wid & (NCHUNK - 1);
  int pg = wid >> 5;
  int g = lane >> 4, n = lane & 15;
  int p = (pg << 2) + g;
  int b = p >> 8, d = p & 255;
  float An = Aneg[d * 16 + n];
  float Dd = Dvec[d];
  float h = h0b[((c << 10) + p) * 16 + n];
  int bl0 = b * 4096 + c * CLEN;
  for (int tt = 0; tt < CLEN; ++tt) {
    size_t bl = bl0 + tt;
    float dl = dlt[bl * 256 + d];
    float xv = xc[bl * 256 + d];
    float Bv = xdbl[bl * 40 + 8 + n];
    float Cv = xdbl[bl * 40 + 24 + n];
    float dA = __expf(dl * An);
    h = dA * h + (dl * xv) * Bv;
    float yc = h * Cv;
    yc += __shfl_xor(yc, 1);
    yc += __shfl_xor(yc, 2);
    yc += __shfl_xor(yc, 4);
    yc += __shfl_xor(yc, 8);
    if (n == 0) {
      float z = xz[bl * 512 + 256 + d];
      float sil = z * (1.f / (1.f + __expf(-z)));
      y2[bl * 256 + d] = (yc + xv * Dd) * sil;
    }
  }
}

// ---------------- out GEMM: 64(l) x 128(c) tile, K=256, + residual ----------------
__global__ __launch_bounds__(256) void gemm_out_kernel(
    const float* __restrict__ y2, const float* __restrict__ Wout,
    const float* __restrict__ x, float* __restrict__ out) {
  __shared__ __align__(16) float ys[64][68];
  __shared__ __align__(16) float ws2[64][132];
  int m0 = blockIdx.x * 64;
  int b = m0 >> 12;
  int l0 = m0 & 4095;
  int tid = threadIdx.x;
  int tx = tid & 7;      // l-group of 8
  int ty = tid >> 3;     // 0..31, c-group of 4
  float acc[8][4] = {};
  for (int kc = 0; kc < 256; kc += 64) {
    #pragma unroll
    for (int jj = 0; jj < 4; ++jj) {
      int i = tid + jj * 256;
      int ml = i >> 4, kq = (i & 15) << 2;
      float4 v = *reinterpret_cast<const float4*>(
          &y2[(size_t)(m0 + ml) * 256 + kc + kq]);
      ys[kq + 0][ml] = v.x; ys[kq + 1][ml] = v.y;
      ys[kq + 2][ml] = v.z; ys[kq + 3][ml] = v.w;
    }
    #pragma unroll
    for (int jj = 0; jj < 8; ++jj) {
      int i = tid + jj * 256;
      int cc = i >> 4, kq = (i & 15) << 2;
      float4 v = *reinterpret_cast<const float4*>(&Wout[(size_t)cc * 256 + kc + kq]);
      ws2[kq + 0][cc] = v.x; ws2[kq + 1][cc] = v.y;
      ws2[kq + 2][cc] = v.z; ws2[kq + 3][cc] = v.w;
    }
    __syncthreads();
    for (int kk = 0; kk < 64; ++kk) {
      float4 xa = *reinterpret_cast<const float4*>(&ys[kk][tx * 8]);
      float4 xb = *reinterpret_cast<const float4*>(&ys[kk][tx * 8 + 4]);
      float4 wa = *reinterpret_cast<const float4*>(&ws2[kk][ty * 4]);
      float xv[8] = {xa.x, xa.y, xa.z, xa.w, xb.x, xb.y, xb.z, xb.w};
      float wv[4] = {wa.x, wa.y, wa.z, wa.w};
      #pragma unroll
      for (int i2 = 0; i2 < 8; ++i2)
        #pragma unroll
        for (int j2 = 0; j2 < 4; ++j2)
          acc[i2][j2] += xv[i2] * wv[j2];
    }
    __syncthreads();
  }
  #pragma unroll
  for (int j2 = 0; j2 < 4; ++j2) {
    int cc = ty * 4 + j2;
    size_t base = ((size_t)(b * 128 + cc)) * 4096 + l0 + tx * 8;
    float4 xa = *reinterpret_cast<const float4*>(&x[base]);
    float4 xb = *reinterpret_cast<const float4*>(&x[base + 4]);
    float4 r0{acc[0][j2] + xa.x, acc[1][j2] + xa.y, acc[2][j2] + xa.z, acc[3][j2] + xa.w};
    float4 r1{acc[4][j2] + xb.x, acc[5][j2] + xb.y, acc[6][j2] + xb.z, acc[7][j2] + xb.w};
    *reinterpret_cast<float4*>(&out[base]) = r0;
    *reinterpret_cast<float4*>(&out[base + 4]) = r1;
  }
}

extern "C" void kernel_launch(void* const* d_in, const int* in_sizes, int n_in,
                              void* d_out, int out_size, void* d_ws, size_t ws_size,
                              hipStream_t stream) {
  const float* x         = (const float*)d_in[0];
  const float* proj_w    = (const float*)d_in[1];
  const float* in_proj_w = (const float*)d_in[2];
  const float* conv_w    = (const float*)d_in[3];
  const float* conv_b    = (const float*)d_in[4];
  const float* x_proj_w  = (const float*)d_in[5];
  const float* dt_proj_w = (const float*)d_in[6];
  const float* dt_proj_b = (const float*)d_in[7];
  const float* A_log     = (const float*)d_in[8];
  const float* Dvec      = (const float*)d_in[9];
  const float* out_proj_w= (const float*)d_in[10];

  float* ws   = (float*)d_ws;
  float* W2   = ws;                  // 65536
  float* wT   = W2 + 65536;          // 10240
  float* Aneg = wT + 10240;          // 4096
  float* xz   = Aneg + 4096;         // 8388608 (32 MB)
  float* xc   = xz + 8388608;        // 4194304 (16 MB)
  float* xdbl = xc + 4194304;        // 655360
  float* dlt  = xdbl + 655360;       // 4194304 (16 MB)
  float* chA  = dlt + 4194304;       // 524288
  float* chH  = chA + 524288;        // 524288
  float* h0b  = chH + 524288;        // 524288
  float* y2   = h0b + 524288;        // 4194304 (16 MB)  -- total ~89 MB
  float* out  = (float*)d_out;

  prep_kernel<<<312, 256, 0, stream>>>(proj_w, in_proj_w, x_proj_w, A_log, W2, wT, Aneg);
  gemm_xz_kernel<<<512, 256, 0, stream>>>(x, W2, xz);
  conv_silu_kernel<<<16384, 256, 0, stream>>>(xz, conv_w, conv_b, xc);
  xdbl_kernel<<<512, 256, 0, stream>>>(xc, wT, xdbl);
  delta_kernel<<<16384, 256, 0, stream>>>(xdbl, dt_proj_w, dt_proj_b, dlt);
  scan1_kernel<<<2048, 256, 0, stream>>>(dlt, xc, xdbl, Aneg, chA, chH);
  scan2_kernel<<<64, 256, 0, stream>>>(chA, chH, h0b);
  scan3_kernel<<<2048, 256, 0, stream>>>(dlt, xc, xdbl, Aneg, h0b, Dvec, xz, y2);
  gemm_out_kernel<<<256, 256, 0, stream>>>(y2, out_proj_w, x, out);
}

// Round 2
// 265.703 us; speedup vs baseline: 1.2787x; 1.2787x over previous
//
#include <hip/hip_runtime.h>

// Mamba2D: B=4, C=128, H=W=64 (L=4096), D_INNER=256, D_STATE=16, DT_RANK=8, D_CONV=4
// fp32 pipeline:
//  prep:       W2 = in_proj_w @ proj_w; wT = x_proj_w^T; Aneg = -exp(A_log)
//  gemm_xz:    xz[b,l,o] = sum_c W2[o,c] * x[b,c,l]
//  conv_silu:  xc = silu(depthwise causal conv4(xz[:,:,:256]) + conv_b)
//  xdbl_delta: BC[b,l,0:32] = (xc @ x_proj_w^T)[8:40]; dlt = softplus(dt_r @ dt_proj_w^T + b)
//  scan (3-phase, chunks of 32, states-in-registers):
//    scan1: per-chunk Sum(dl) and local h[16]      (lane = (b,d) pair)
//    scan2: chunk prefix, seeds written in-place into chH
//    scan3: replay + y = h.C, fused epilogue y2 = (y + xc*D)*silu(z)   [y2 aliases dlt]
//  gemm_out:   out[b,c,l] = Wout @ y2 + x

#define NCHUNK 128
#define CLEN 32

// ---------------- prep ----------------
__global__ void prep_kernel(const float* __restrict__ proj_w,
                            const float* __restrict__ in_proj_w,
                            const float* __restrict__ x_proj_w,
                            const float* __restrict__ A_log,
                            float* __restrict__ W2,
                            float* __restrict__ wT,
                            float* __restrict__ Aneg) {
  int idx = blockIdx.x * blockDim.x + threadIdx.x;
  if (idx < 512 * 128) {
    int o = idx >> 7, c = idx & 127;
    float acc = 0.f;
    #pragma unroll 4
    for (int i = 0; i < 128; ++i)
      acc += in_proj_w[o * 128 + i] * proj_w[i * 128 + c];
    W2[idx] = acc;
  } else if (idx < 512 * 128 + 256 * 40) {
    int t = idx - 512 * 128;
    int k = t / 40, j = t % 40;
    wT[t] = x_proj_w[j * 256 + k];
  } else if (idx < 512 * 128 + 256 * 40 + 256 * 16) {
    int t = idx - (512 * 128 + 256 * 40);
    Aneg[t] = -__expf(A_log[t]);
  }
}

// ---------------- xz GEMM: 128x128 tile, 8x8 register tile ----------------
__global__ __launch_bounds__(256) void gemm_xz_kernel(
    const float* __restrict__ x, const float* __restrict__ W2,
    float* __restrict__ xz) {
  __shared__ __align__(16) float xs[64][132];
  __shared__ __align__(16) float ws[64][132];
  int mt = blockIdx.x >> 2;
  int nt = blockIdx.x & 3;
  int m0 = mt * 128;
  int b  = m0 >> 12;
  int l0 = m0 & 4095;
  int o0 = nt * 128;
  int tid = threadIdx.x;
  int tx = tid & 15, ty = tid >> 4;
  float acc[8][8] = {};
  for (int kc = 0; kc < 128; kc += 64) {
    #pragma unroll
    for (int j = 0; j < 8; ++j) {
      int i = tid + j * 256;
      int kk = i >> 5, colq = (i & 31) << 2;
      float4 v = *reinterpret_cast<const float4*>(
          &x[((size_t)(b * 128 + kc + kk)) * 4096 + l0 + colq]);
      *reinterpret_cast<float4*>(&xs[kk][colq]) = v;
    }
    #pragma unroll
    for (int j = 0; j < 8; ++j) {
      int i = tid + j * 256;
      int o = i >> 4, kq = (i & 15) << 2;
      float4 v = *reinterpret_cast<const float4*>(&W2[(o0 + o) * 128 + kc + kq]);
      ws[kq + 0][o] = v.x; ws[kq + 1][o] = v.y;
      ws[kq + 2][o] = v.z; ws[kq + 3][o] = v.w;
    }
    __syncthreads();
    for (int kk = 0; kk < 64; ++kk) {
      float4 xa = *reinterpret_cast<const float4*>(&xs[kk][tx * 8]);
      float4 xb = *reinterpret_cast<const float4*>(&xs[kk][tx * 8 + 4]);
      float4 wa = *reinterpret_cast<const float4*>(&ws[kk][ty * 8]);
      float4 wb = *reinterpret_cast<const float4*>(&ws[kk][ty * 8 + 4]);
      float xv[8] = {xa.x, xa.y, xa.z, xa.w, xb.x, xb.y, xb.z, xb.w};
      float wv[8] = {wa.x, wa.y, wa.z, wa.w, wb.x, wb.y, wb.z, wb.w};
      #pragma unroll
      for (int i2 = 0; i2 < 8; ++i2)
        #pragma unroll
        for (int j2 = 0; j2 < 8; ++j2)
          acc[i2][j2] += xv[i2] * wv[j2];
    }
    __syncthreads();
  }
  #pragma unroll
  for (int i2 = 0; i2 < 8; ++i2) {
    size_t row = (size_t)(m0 + tx * 8 + i2) * 512 + o0 + ty * 8;
    float4 a{acc[i2][0], acc[i2][1], acc[i2][2], acc[i2][3]};
    float4 bq{acc[i2][4], acc[i2][5], acc[i2][6], acc[i2][7]};
    *reinterpret_cast<float4*>(&xz[row]) = a;
    *reinterpret_cast<float4*>(&xz[row + 4]) = bq;
  }
}

// ---------------- causal depthwise conv4 + silu ----------------
__global__ void conv_silu_kernel(const float* __restrict__ xz,
                                 const float* __restrict__ conv_w,
                                 const float* __restrict__ conv_b,
                                 float* __restrict__ xc) {
  int bl = blockIdx.x;
  int l = bl & 4095;
  int d = threadIdx.x;
  float acc = conv_b[d];
  #pragma unroll
  for (int k = 0; k < 4; ++k) {
    int ls = l - 3 + k;
    if (ls >= 0)
      acc += conv_w[d * 4 + k] * xz[((size_t)(bl - 3 + k)) * 512 + d];
  }
  float s = acc * (1.f / (1.f + __expf(-acc)));
  xc[(size_t)bl * 256 + d] = s;
}

// ---------------- fused x_dbl GEMM (cols 8..39 -> BC) + delta ----------------
__global__ __launch_bounds__(256) void xdbl_delta_kernel(
    const float* __restrict__ xc, const float* __restrict__ wT,
    const float* __restrict__ dt_proj_w, const float* __restrict__ dt_proj_b,
    float* __restrict__ BC, float* __restrict__ dlt) {
  __shared__ __align__(16) float lx[32][256];
  __shared__ float sdtr[32][8];
  int m0 = blockIdx.x * 32;
  int tid = threadIdx.x;
  #pragma unroll
  for (int jj = 0; jj < 8; ++jj) {
    int i = tid + jj * 256;
    int row = i >> 6, colq = (i & 63) << 2;
    *reinterpret_cast<float4*>(&lx[row][colq]) =
        *reinterpret_cast<const float4*>(&xc[(size_t)(m0 + row) * 256 + colq]);
  }
  __syncthreads();
  int j = tid & 63, g = tid >> 6;
  bool act = j < 40;
  float acc[8] = {};
  for (int k = 0; k < 256; ++k) {
    float w = act ? wT[k * 40 + j] : 0.f;
    #pragma unroll
    for (int i = 0; i < 8; ++i)
      acc[i] += lx[g * 8 + i][k] * w;
  }
  if (j < 8) {
    #pragma unroll
    for (int i = 0; i < 8; ++i)
      sdtr[g * 8 + i][j] = acc[i];
  } else if (j < 40) {
    #pragma unroll
    for (int i = 0; i < 8; ++i)
      BC[(size_t)(m0 + g * 8 + i) * 32 + (j - 8)] = acc[i];
  }
  __syncthreads();
  // delta: thread = one d, 32 rows
  float wrow[8];
  #pragma unroll
  for (int r = 0; r < 8; ++r) wrow[r] = dt_proj_w[tid * 8 + r];
  float bb = dt_proj_b[tid];
  #pragma unroll 4
  for (int r = 0; r < 32; ++r) {
    float a = bb;
    #pragma unroll
    for (int q = 0; q < 8; ++q) a += sdtr[r][q] * wrow[q];
    float sp = fmaxf(a, 0.f) + __logf(1.f + __expf(-fabsf(a)));
    dlt[(size_t)(m0 + r) * 256 + tid] = sp;
  }
}

// ---------------- scan phase 1: per-chunk Sum(dl), local h[16] ----------------
__global__ __launch_bounds__(256) void scan1_kernel(
    const float* __restrict__ dlt, const float* __restrict__ xc,
    const float* __restrict__ BC, const float* __restrict__ Aneg,
    float* __restrict__ Ssum, float* __restrict__ chH) {
  __shared__ __align__(16) float lBC[CLEN][32];
  int bc = blockIdx.x;            // b*128 + c
  int b = bc >> 7, c = bc & 127;
  int d = threadIdx.x;
  int bl0 = b * 4096 + c * CLEN;
  {
    int t = threadIdx.x >> 3, q = (threadIdx.x & 7) << 2;
    *reinterpret_cast<float4*>(&lBC[t][q]) =
        *reinterpret_cast<const float4*>(&BC[(size_t)(bl0 + t) * 32 + q]);
  }
  float An[16];
  #pragma unroll
  for (int q = 0; q < 4; ++q)
    *reinterpret_cast<float4*>(&An[q * 4]) =
        *reinterpret_cast<const float4*>(&Aneg[d * 16 + q * 4]);
  float dl[CLEN], xv[CLEN];
  #pragma unroll
  for (int t = 0; t < CLEN; ++t) {
    dl[t] = dlt[(size_t)(bl0 + t) * 256 + d];
    xv[t] = xc[(size_t)(bl0 + t) * 256 + d];
  }
  float h[16] = {};
  float S = 0.f;
  __syncthreads();
  #pragma unroll
  for (int t = 0; t < CLEN; ++t) {
    float dlv = dl[t];
    float dlx = dlv * xv[t];
    S += dlv;
    float4 B0 = *reinterpret_cast<const float4*>(&lBC[t][0]);
    float4 B1 = *reinterpret_cast<const float4*>(&lBC[t][4]);
    float4 B2 = *reinterpret_cast<const float4*>(&lBC[t][8]);
    float4 B3 = *reinterpret_cast<const float4*>(&lBC[t][12]);
    float Bv[16] = {B0.x,B0.y,B0.z,B0.w,B1.x,B1.y,B1.z,B1.w,
                    B2.x,B2.y,B2.z,B2.w,B3.x,B3.y,B3.z,B3.w};
    #pragma unroll
    for (int n = 0; n < 16; ++n)
      h[n] = __expf(dlv * An[n]) * h[n] + dlx * Bv[n];
  }
  int p = b * 256 + d;
  Ssum[c * 1024 + p] = S;
  size_t base = ((size_t)(c * 1024 + p)) * 16;
  #pragma unroll
  for (int q = 0; q < 4; ++q) {
    float4 v{h[q*4+0], h[q*4+1], h[q*4+2], h[q*4+3]};
    *reinterpret_cast<float4*>(&chH[base + q * 4]) = v;
  }
}

// ---------------- scan phase 2: chunk prefix, seeds in-place ----------------
__global__ void scan2_kernel(const float* __restrict__ Aneg,
                             const float* __restrict__ Ssum,
                             float* chH) {
  int q = blockIdx.x * blockDim.x + threadIdx.x;  // 0..16383
  int p = q >> 4, n = q & 15;
  int d = p & 255;
  float An = Aneg[d * 16 + n];
  float h = 0.f;
  #pragma unroll 4
  for (int c = 0; c < NCHUNK; ++c) {
    size_t idx = ((size_t)(c * 1024 + p)) * 16 + n;
    float S = Ssum[c * 1024 + p];
    float tmp = chH[idx];
    chH[idx] = h;                    // seed = state before chunk c
    h = __expf(An * S) * h + tmp;
  }
}

// ---------------- scan phase 3: replay + y, fused epilogue ----------------
// NOTE: y2 aliases dlt (element-wise disjoint in time: all dlt reads for this
// block's rows are preloaded before any y2 store). No restrict on those two.
__global__ __launch_bounds__(256) void scan3_kernel(
    const float* dlt, const float* __restrict__ xc,
    const float* __restrict__ BC, const float* __restrict__ Aneg,
    const float* __restrict__ chH, const float* __restrict__ Dvec,
    const float* __restrict__ xz, float* y2) {
  __shared__ __align__(16) float lBC[CLEN][32];
  int bc = blockIdx.x;
  int b = bc >> 7, c = bc & 127;
  int d = threadIdx.x;
  int bl0 = b * 4096 + c * CLEN;
  {
    int t = threadIdx.x >> 3, q = (threadIdx.x & 7) << 2;
    *reinterpret_cast<float4*>(&lBC[t][q]) =
        *reinterpret_cast<const float4*>(&BC[(size_t)(bl0 + t) * 32 + q]);
  }
  float An[16];
  #pragma unroll
  for (int q = 0; q < 4; ++q)
    *reinterpret_cast<float4*>(&An[q * 4]) =
        *reinterpret_cast<const float4*>(&Aneg[d * 16 + q * 4]);
  int p = b * 256 + d;
  float h[16];
  {
    size_t base = ((size_t)(c * 1024 + p)) * 16;
    #pragma unroll
    for (int q = 0; q < 4; ++q) {
      float4 v = *reinterpret_cast<const float4*>(&chH[base + q * 4]);
      h[q*4+0] = v.x; h[q*4+1] = v.y; h[q*4+2] = v.z; h[q*4+3] = v.w;
    }
  }
  float dl[CLEN], xv[CLEN], zv[CLEN];
  #pragma unroll
  for (int t = 0; t < CLEN; ++t) {
    dl[t] = dlt[(size_t)(bl0 + t) * 256 + d];
    xv[t] = xc[(size_t)(bl0 + t) * 256 + d];
    zv[t] = xz[(size_t)(bl0 + t) * 512 + 256 + d];
  }
  float Dd = Dvec[d];
  __syncthreads();
  #pragma unroll
  for (int t = 0; t < CLEN; ++t) {
    float dlv = dl[t];
    float xvv = xv[t];
    float dlx = dlv * xvv;
    float4 B0 = *reinterpret_cast<const float4*>(&lBC[t][0]);
    float4 B1 = *reinterpret_cast<const float4*>(&lBC[t][4]);
    float4 B2 = *reinterpret_cast<const float4*>(&lBC[t][8]);
    float4 B3 = *reinterpret_cast<const float4*>(&lBC[t][12]);
    float4 C0 = *reinterpret_cast<const float4*>(&lBC[t][16]);
    float4 C1 = *reinterpret_cast<const float4*>(&lBC[t][20]);
    float4 C2 = *reinterpret_cast<const float4*>(&lBC[t][24]);
    float4 C3 = *reinterpret_cast<const float4*>(&lBC[t][28]);
    float Bv[16] = {B0.x,B0.y,B0.z,B0.w,B1.x,B1.y,B1.z,B1.w,
                    B2.x,B2.y,B2.z,B2.w,B3.x,B3.y,B3.z,B3.w};
    float Cv[16] = {C0.x,C0.y,C0.z,C0.w,C1.x,C1.y,C1.z,C1.w,
                    C2.x,C2.y,C2.z,C2.w,C3.x,C3.y,C3.z,C3.w};
    float y = 0.f;
    #pragma unroll
    for (int n = 0; n < 16; ++n) {
      h[n] = __expf(dlv * An[n]) * h[n] + dlx * Bv[n];
      y += h[n] * Cv[n];
    }
    float z = zv[t];
    float sil = z * (1.f / (1.f + __expf(-z)));
    y2[(size_t)(bl0 + t) * 256 + d] = (y + xvv * Dd) * sil;
  }
}

// ---------------- out GEMM: 64(l) x 128(c) tile, K=256, + residual ----------------
__global__ __launch_bounds__(256) void gemm_out_kernel(
    const float* __restrict__ y2, const float* __restrict__ Wout,
    const float* __restrict__ x, float* __restrict__ out) {
  __shared__ __align__(16) float ys[64][68];
  __shared__ __align__(16) float ws2[64][132];
  int m0 = blockIdx.x * 64;
  int b = m0 >> 12;
  int l0 = m0 & 4095;
  int tid = threadIdx.x;
  int tx = tid & 7;
  int ty = tid >> 3;
  float acc[8][4] = {};
  for (int kc = 0; kc < 256; kc += 64) {
    #pragma unroll
    for (int jj = 0; jj < 4; ++jj) {
      int i = tid + jj * 256;
      int ml = i >> 4, kq = (i & 15) << 2;
      float4 v = *reinterpret_cast<const float4*>(
          &y2[(size_t)(m0 + ml) * 256 + kc + kq]);
      ys[kq + 0][ml] = v.x; ys[kq + 1][ml] = v.y;
      ys[kq + 2][ml] = v.z; ys[kq + 3][ml] = v.w;
    }
    #pragma unroll
    for (int jj = 0; jj < 8; ++jj) {
      int i = tid + jj * 256;
      int cc = i >> 4, kq = (i & 15) << 2;
      float4 v = *reinterpret_cast<const float4*>(&Wout[(size_t)cc * 256 + kc + kq]);
      ws2[kq + 0][cc] = v.x; ws2[kq + 1][cc] = v.y;
      ws2[kq + 2][cc] = v.z; ws2[kq + 3][cc] = v.w;
    }
    __syncthreads();
    for (int kk = 0; kk < 64; ++kk) {
      float4 xa = *reinterpret_cast<const float4*>(&ys[kk][tx * 8]);
      float4 xb = *reinterpret_cast<const float4*>(&ys[kk][tx * 8 + 4]);
      float4 wa = *reinterpret_cast<const float4*>(&ws2[kk][ty * 4]);
      float xv[8] = {xa.x, xa.y, xa.z, xa.w, xb.x, xb.y, xb.z, xb.w};
      float wv[4] = {wa.x, wa.y, wa.z, wa.w};
      #pragma unroll
      for (int i2 = 0; i2 < 8; ++i2)
        #pragma unroll
        for (int j2 = 0; j2 < 4; ++j2)
          acc[i2][j2] += xv[i2] * wv[j2];
    }
    __syncthreads();
  }
  #pragma unroll
  for (int j2 = 0; j2 < 4; ++j2) {
    int cc = ty * 4 + j2;
    size_t base = ((size_t)(b * 128 + cc)) * 4096 + l0 + tx * 8;
    float4 xa = *reinterpret_cast<const float4*>(&x[base]);
    float4 xb = *reinterpret_cast<const float4*>(&x[base + 4]);
    float4 r0{acc[0][j2] + xa.x, acc[1][j2] + xa.y, acc[2][j2] + xa.z, acc[3][j2] + xa.w};
    float4 r1{acc[4][j2] + xb.x, acc[5][j2] + xb.y, acc[6][j2] + xb.z, acc[7][j2] + xb.w};
    *reinterpret_cast<float4*>(&out[base]) = r0;
    *reinterpret_cast<float4*>(&out[base + 4]) = r1;
  }
}

extern "C" void kernel_launch(void* const* d_in, const int* in_sizes, int n_in,
                              void* d_out, int out_size, void* d_ws, size_t ws_size,
                              hipStream_t stream) {
  const float* x         = (const float*)d_in[0];
  const float* proj_w    = (const float*)d_in[1];
  const float* in_proj_w = (const float*)d_in[2];
  const float* conv_w    = (const float*)d_in[3];
  const float* conv_b    = (const float*)d_in[4];
  const float* x_proj_w  = (const float*)d_in[5];
  const float* dt_proj_w = (const float*)d_in[6];
  const float* dt_proj_b = (const float*)d_in[7];
  const float* A_log     = (const float*)d_in[8];
  const float* Dvec      = (const float*)d_in[9];
  const float* out_proj_w= (const float*)d_in[10];

  float* ws   = (float*)d_ws;
  float* W2   = ws;                   // 65536
  float* wT   = W2 + 65536;           // 10240
  float* Aneg = wT + 10240;           // 4096
  float* xz   = Aneg + 4096;          // 8388608 (32 MB)
  float* xc   = xz + 8388608;         // 4194304 (16 MB)
  float* BC   = xc + 4194304;         // 524288  (2 MB)
  float* dlt  = BC + 524288;          // 4194304 (16 MB) -- also y2 (aliased)
  float* Ssum = dlt + 4194304;        // 131072
  float* chH  = Ssum + 131072;        // 2097152 (8 MB)   total ~78.5 MB
  float* y2   = dlt;                  // alias: see scan3 note
  float* out  = (float*)d_out;

  prep_kernel<<<312, 256, 0, stream>>>(proj_w, in_proj_w, x_proj_w, A_log, W2, wT, Aneg);
  gemm_xz_kernel<<<512, 256, 0, stream>>>(x, W2, xz);
  conv_silu_kernel<<<16384, 256, 0, stream>>>(xz, conv_w, conv_b, xc);
  xdbl_delta_kernel<<<512, 256, 0, stream>>>(xc, wT, dt_proj_w, dt_proj_b, BC, dlt);
  scan1_kernel<<<512, 256, 0, stream>>>(dlt, xc, BC, Aneg, Ssum, chH);
  scan2_kernel<<<64, 256, 0, stream>>>(Aneg, Ssum, chH);
  scan3_kernel<<<512, 256, 0, stream>>>(dlt, xc, BC, Aneg, chH, Dvec, xz, y2);
  gemm_out_kernel<<<256, 256, 0, stream>>>(y2, out_proj_w, x, out);
}

// Round 3
// 220.087 us; speedup vs baseline: 1.5437x; 1.2073x over previous
//
#include <hip/hip_runtime.h>

// Mamba2D: B=4, C=128, H=W=64 (L=4096), D_INNER=256, D_STATE=16, DT_RANK=8, D_CONV=4
//  prep:        W2b = bf16(in_proj_w @ proj_w); wT = x_proj_w^T; Aneg = -exp(A_log)
//  gemm_xz:     bf16 MFMA, xz[b,l,o] = sum_c W2[o,c]*x[b,c,l]  (M=16384,N=512,K=128)
//  conv_silu:   xc = silu(depthwise causal conv4(xz[:,:,:256]) + conv_b), 8 rows/block
//  xdbl_scan1:  fused: BC/dlt = projections; per-chunk scan (32 steps, h[16] in regs)
//  scan2:       chunk prefix (restrict in/out buffers -> pipelined loads)
//  scan3:       replay + y, fused epilogue y2=(y+xc*D)*silu(z)   [y2 aliases dlt]
//  gemm_out:    fp32 tiled, out = Wout @ y2 + x

#define NCHUNK 128
#define CLEN 32

using s16x8 = __attribute__((ext_vector_type(8))) short;
using f32x4 = __attribute__((ext_vector_type(4))) float;

__device__ inline unsigned short f2bf(float f) {
  unsigned u = __float_as_uint(f);
  u = u + 0x7FFF + ((u >> 16) & 1);
  return (unsigned short)(u >> 16);
}

// ---------------- prep ----------------
__global__ void prep_kernel(const float* __restrict__ proj_w,
                            const float* __restrict__ in_proj_w,
                            const float* __restrict__ x_proj_w,
                            const float* __restrict__ A_log,
                            unsigned short* __restrict__ W2b,
                            float* __restrict__ wT,
                            float* __restrict__ Aneg) {
  int idx = blockIdx.x * blockDim.x + threadIdx.x;
  if (idx < 512 * 128) {
    int o = idx >> 7, c = idx & 127;
    float acc = 0.f;
    #pragma unroll 4
    for (int i = 0; i < 128; ++i)
      acc += in_proj_w[o * 128 + i] * proj_w[i * 128 + c];
    W2b[idx] = f2bf(acc);
  } else if (idx < 512 * 128 + 256 * 40) {
    int t = idx - 512 * 128;
    int k = t / 40, j = t % 40;
    wT[t] = x_proj_w[j * 256 + k];
  } else if (idx < 512 * 128 + 256 * 40 + 256 * 16) {
    int t = idx - (512 * 128 + 256 * 40);
    Aneg[t] = -__expf(A_log[t]);
  }
}

// ---------------- xz GEMM via bf16 MFMA ----------------
// Tile: 128 m (b,l) x 256 n (o), K=128. 4 waves: wm in {0,1} (64 m), wn in {0,1} (128 n).
// LDS: Atile[l][c] bf16 (x transposed in staging), Btile[o][c] bf16; both k-contiguous,
// 16B-granule XOR swizzle  g ^= (row&7)<<1  to break the stride-256B bank collision.
__global__ __launch_bounds__(256, 1) void gemm_xz_kernel(
    const float* __restrict__ x, const unsigned short* __restrict__ W2b,
    float* __restrict__ xz) {
  __shared__ __align__(16) unsigned short At[128 * 128];
  __shared__ __align__(16) unsigned short Bt[256 * 128];
  int m0 = (blockIdx.x >> 1) * 128;
  int o0 = (blockIdx.x & 1) * 256;
  int b  = m0 >> 12;
  int l0 = m0 & 4095;
  int t = threadIdx.x;
  // stage A: read x[b, c, l0+..] coalesced fp32, write bf16 transposed+swizzled
  #pragma unroll
  for (int j = 0; j < 16; ++j) {
    int flat = t + j * 256;
    int cr = flat >> 5, lq = (flat & 31) << 2;
    float4 v = *reinterpret_cast<const float4*>(
        &x[((size_t)(b * 128 + cr)) * 4096 + l0 + lq]);
    float vv[4] = {v.x, v.y, v.z, v.w};
    #pragma unroll
    for (int e = 0; e < 4; ++e) {
      int l = lq + e;
      int g = (cr >> 3) ^ ((l & 7) << 1);
      At[l * 128 + g * 8 + (cr & 7)] = f2bf(vv[e]);
    }
  }
  // stage B: W2b rows (k-contiguous), swizzled granules
  #pragma unroll
  for (int j = 0; j < 16; ++j) {
    int flat = t + j * 256;
    int row = flat >> 4, gB = flat & 15;
    s16x8 v = *reinterpret_cast<const s16x8*>(&W2b[(size_t)(o0 + row) * 128 + gB * 8]);
    int g = gB ^ ((row & 7) << 1);
    *reinterpret_cast<s16x8*>(&Bt[row * 128 + g * 8]) = v;
  }
  __syncthreads();
  int ln = t & 63, wave = t >> 6;
  int wm = wave & 1, wn = wave >> 1;
  f32x4 acc[4][8] = {};
  #pragma unroll
  for (int ks = 0; ks < 4; ++ks) {
    int gk = ks * 4 + (ln >> 4);
    s16x8 a[4], bb[8];
    #pragma unroll
    for (int mi = 0; mi < 4; ++mi) {
      int lr = wm * 64 + mi * 16 + (ln & 15);
      a[mi] = *reinterpret_cast<const s16x8*>(&At[lr * 128 + (gk ^ ((lr & 7) << 1)) * 8]);
    }
    #pragma unroll
    for (int ni = 0; ni < 8; ++ni) {
      int orow = wn * 128 + ni * 16 + (ln & 15);
      bb[ni] = *reinterpret_cast<const s16x8*>(&Bt[orow * 128 + (gk ^ ((orow & 7) << 1)) * 8]);
    }
    #pragma unroll
    for (int mi = 0; mi < 4; ++mi)
      #pragma unroll
      for (int ni = 0; ni < 8; ++ni)
        acc[mi][ni] = __builtin_amdgcn_mfma_f32_16x16x32_bf16(a[mi], bb[ni], acc[mi][ni], 0, 0, 0);
  }
  #pragma unroll
  for (int mi = 0; mi < 4; ++mi)
    #pragma unroll
    for (int ni = 0; ni < 8; ++ni)
      #pragma unroll
      for (int r = 0; r < 4; ++r) {
        int row = wm * 64 + mi * 16 + (ln >> 4) * 4 + r;
        int col = wn * 128 + ni * 16 + (ln & 15);
        xz[(size_t)(m0 + row) * 512 + o0 + col] = acc[mi][ni][r];
      }
}

// ---------------- causal depthwise conv4 + silu (8 rows/block, sliding) ----------------
__global__ __launch_bounds__(256) void conv_silu_kernel(
    const float* __restrict__ xz, const float* __restrict__ conv_w,
    const float* __restrict__ conv_b, float* __restrict__ xc) {
  int bl0 = blockIdx.x * 8;
  int d = threadIdx.x;
  int l0 = bl0 & 4095;
  float w0 = conv_w[d * 4 + 0], w1 = conv_w[d * 4 + 1];
  float w2 = conv_w[d * 4 + 2], w3 = conv_w[d * 4 + 3];
  float cb = conv_b[d];
  float xm1 = (l0 >= 1) ? xz[(size_t)(bl0 - 1) * 512 + d] : 0.f;
  float xm2 = (l0 >= 2) ? xz[(size_t)(bl0 - 2) * 512 + d] : 0.f;
  float xm3 = (l0 >= 3) ? xz[(size_t)(bl0 - 3) * 512 + d] : 0.f;
  #pragma unroll
  for (int r = 0; r < 8; ++r) {
    size_t bl = bl0 + r;
    float x0 = xz[bl * 512 + d];
    float acc = cb + w3 * x0 + w2 * xm1 + w1 * xm2 + w0 * xm3;
    float s = acc * (1.f / (1.f + __expf(-acc)));
    xc[bl * 256 + d] = s;
    xm3 = xm2; xm2 = xm1; xm1 = x0;
  }
}

// ---------------- fused x_dbl GEMM + delta + scan phase 1 ----------------
// block = one (b, chunk): 32 rows. 512 blocks.
__global__ __launch_bounds__(256) void xdbl_scan1_kernel(
    const float* __restrict__ xc, const float* __restrict__ wT,
    const float* __restrict__ dt_proj_w, const float* __restrict__ dt_proj_b,
    const float* __restrict__ Aneg,
    float* __restrict__ BC, float* __restrict__ dlt,
    float* __restrict__ Ssum, float* __restrict__ chH) {
  __shared__ __align__(16) float lx[32][256];
  __shared__ float sdtr[32][8];
  __shared__ __align__(16) float lBC[32][32];
  int bc = blockIdx.x;
  int b = bc >> 7, c = bc & 127;
  int m0 = bc * 32;
  int tid = threadIdx.x;
  #pragma unroll
  for (int jj = 0; jj < 8; ++jj) {
    int i = tid + jj * 256;
    int row = i >> 6, colq = (i & 63) << 2;
    *reinterpret_cast<float4*>(&lx[row][colq]) =
        *reinterpret_cast<const float4*>(&xc[(size_t)(m0 + row) * 256 + colq]);
  }
  __syncthreads();
  // x_dbl GEMM: col j (0..39), row-group g
  {
    int j = tid & 63, g = tid >> 6;
    bool act = j < 40;
    float acc[8] = {};
    for (int k = 0; k < 256; ++k) {
      float w = act ? wT[k * 40 + j] : 0.f;
      #pragma unroll
      for (int i = 0; i < 8; ++i)
        acc[i] += lx[g * 8 + i][k] * w;
    }
    if (j < 8) {
      #pragma unroll
      for (int i = 0; i < 8; ++i)
        sdtr[g * 8 + i][j] = acc[i];
    } else if (j < 40) {
      #pragma unroll
      for (int i = 0; i < 8; ++i) {
        BC[(size_t)(m0 + g * 8 + i) * 32 + (j - 8)] = acc[i];
        lBC[g * 8 + i][j - 8] = acc[i];
      }
    }
  }
  __syncthreads();
  // delta for this thread's d over 32 rows (kept in regs for scan)
  int d = tid;
  float dl_r[32];
  {
    float wrow[8];
    #pragma unroll
    for (int r = 0; r < 8; ++r) wrow[r] = dt_proj_w[d * 8 + r];
    float bb = dt_proj_b[d];
    #pragma unroll 4
    for (int r = 0; r < 32; ++r) {
      float a = bb;
      #pragma unroll
      for (int q = 0; q < 8; ++q) a += sdtr[r][q] * wrow[q];
      float sp = fmaxf(a, 0.f) + __logf(1.f + __expf(-fabsf(a)));
      dl_r[r] = sp;
      dlt[(size_t)(m0 + r) * 256 + d] = sp;
    }
  }
  // scan phase 1: h[16] recurrence, Sum(dl)
  float An[16];
  #pragma unroll
  for (int q = 0; q < 4; ++q)
    *reinterpret_cast<float4*>(&An[q * 4]) =
        *reinterpret_cast<const float4*>(&Aneg[d * 16 + q * 4]);
  float h[16] = {};
  float S = 0.f;
  #pragma unroll
  for (int t = 0; t < CLEN; ++t) {
    float dlv = dl_r[t];
    float dlx = dlv * lx[t][d];
    S += dlv;
    float4 B0 = *reinterpret_cast<const float4*>(&lBC[t][0]);
    float4 B1 = *reinterpret_cast<const float4*>(&lBC[t][4]);
    float4 B2 = *reinterpret_cast<const float4*>(&lBC[t][8]);
    float4 B3 = *reinterpret_cast<const float4*>(&lBC[t][12]);
    float Bv[16] = {B0.x,B0.y,B0.z,B0.w,B1.x,B1.y,B1.z,B1.w,
                    B2.x,B2.y,B2.z,B2.w,B3.x,B3.y,B3.z,B3.w};
    #pragma unroll
    for (int n = 0; n < 16; ++n)
      h[n] = __expf(dlv * An[n]) * h[n] + dlx * Bv[n];
  }
  int p = b * 256 + d;
  Ssum[c * 1024 + p] = S;
  size_t base = ((size_t)(c * 1024 + p)) * 16;
  #pragma unroll
  for (int q = 0; q < 4; ++q) {
    float4 v{h[q*4+0], h[q*4+1], h[q*4+2], h[q*4+3]};
    *reinterpret_cast<float4*>(&chH[base + q * 4]) = v;
  }
}

// ---------------- scan phase 2: chunk prefix (pipelined loads) ----------------
__global__ void scan2_kernel(const float* __restrict__ Aneg,
                             const float* __restrict__ Ssum,
                             const float* __restrict__ chH,
                             float* __restrict__ chS) {
  int q = blockIdx.x * blockDim.x + threadIdx.x;  // 0..16383
  int p = q >> 4, n = q & 15;
  int d = p & 255;
  float An = Aneg[d * 16 + n];
  float h = 0.f;
  #pragma unroll 8
  for (int c = 0; c < NCHUNK; ++c) {
    size_t idx = ((size_t)(c * 1024 + p)) * 16 + n;
    float S = Ssum[c * 1024 + p];
    float hl = chH[idx];
    chS[idx] = h;
    h = __expf(An * S) * h + hl;
  }
}

// ---------------- scan phase 3: replay + y, fused epilogue ----------------
// y2 aliases dlt: all dlt reads for this block's rows are preloaded before stores.
__global__ __launch_bounds__(256) void scan3_kernel(
    const float* dlt, const float* __restrict__ xc,
    const float* __restrict__ BC, const float* __restrict__ Aneg,
    const float* __restrict__ chS, const float* __restrict__ Dvec,
    const float* __restrict__ xz, float* y2) {
  __shared__ __align__(16) float lBC[CLEN][32];
  int bc = blockIdx.x;
  int b = bc >> 7, c = bc & 127;
  int d = threadIdx.x;
  int bl0 = b * 4096 + c * CLEN;
  {
    int t = threadIdx.x >> 3, q = (threadIdx.x & 7) << 2;
    *reinterpret_cast<float4*>(&lBC[t][q]) =
        *reinterpret_cast<const float4*>(&BC[(size_t)(bl0 + t) * 32 + q]);
  }
  float An[16];
  #pragma unroll
  for (int q = 0; q < 4; ++q)
    *reinterpret_cast<float4*>(&An[q * 4]) =
        *reinterpret_cast<const float4*>(&Aneg[d * 16 + q * 4]);
  int p = b * 256 + d;
  float h[16];
  {
    size_t base = ((size_t)(c * 1024 + p)) * 16;
    #pragma unroll
    for (int q = 0; q < 4; ++q) {
      float4 v = *reinterpret_cast<const float4*>(&chS[base + q * 4]);
      h[q*4+0] = v.x; h[q*4+1] = v.y; h[q*4+2] = v.z; h[q*4+3] = v.w;
    }
  }
  float dl[CLEN], xv[CLEN], zv[CLEN];
  #pragma unroll
  for (int t = 0; t < CLEN; ++t) {
    dl[t] = dlt[(size_t)(bl0 + t) * 256 + d];
    xv[t] = xc[(size_t)(bl0 + t) * 256 + d];
    zv[t] = xz[(size_t)(bl0 + t) * 512 + 256 + d];
  }
  float Dd = Dvec[d];
  __syncthreads();
  #pragma unroll
  for (int t = 0; t < CLEN; ++t) {
    float dlv = dl[t];
    float xvv = xv[t];
    float dlx = dlv * xvv;
    float4 B0 = *reinterpret_cast<const float4*>(&lBC[t][0]);
    float4 B1 = *reinterpret_cast<const float4*>(&lBC[t][4]);
    float4 B2 = *reinterpret_cast<const float4*>(&lBC[t][8]);
    float4 B3 = *reinterpret_cast<const float4*>(&lBC[t][12]);
    float4 C0 = *reinterpret_cast<const float4*>(&lBC[t][16]);
    float4 C1 = *reinterpret_cast<const float4*>(&lBC[t][20]);
    float4 C2 = *reinterpret_cast<const float4*>(&lBC[t][24]);
    float4 C3 = *reinterpret_cast<const float4*>(&lBC[t][28]);
    float Bv[16] = {B0.x,B0.y,B0.z,B0.w,B1.x,B1.y,B1.z,B1.w,
                    B2.x,B2.y,B2.z,B2.w,B3.x,B3.y,B3.z,B3.w};
    float Cv[16] = {C0.x,C0.y,C0.z,C0.w,C1.x,C1.y,C1.z,C1.w,
                    C2.x,C2.y,C2.z,C2.w,C3.x,C3.y,C3.z,C3.w};
    float y = 0.f;
    #pragma unroll
    for (int n = 0; n < 16; ++n) {
      h[n] = __expf(dlv * An[n]) * h[n] + dlx * Bv[n];
      y += h[n] * Cv[n];
    }
    float z = zv[t];
    float sil = z * (1.f / (1.f + __expf(-z)));
    y2[(size_t)(bl0 + t) * 256 + d] = (y + xvv * Dd) * sil;
  }
}

// ---------------- out GEMM: 64(l) x 128(c) tile, K=256, + residual ----------------
__global__ __launch_bounds__(256) void gemm_out_kernel(
    const float* __restrict__ y2, const float* __restrict__ Wout,
    const float* __restrict__ x, float* __restrict__ out) {
  __shared__ __align__(16) float ys[64][68];
  __shared__ __align__(16) float ws2[64][132];
  int m0 = blockIdx.x * 64;
  int b = m0 >> 12;
  int l0 = m0 & 4095;
  int tid = threadIdx.x;
  int tx = tid & 7;
  int ty = tid >> 3;
  float acc[8][4] = {};
  for (int kc = 0; kc < 256; kc += 64) {
    #pragma unroll
    for (int jj = 0; jj < 4; ++jj) {
      int i = tid + jj * 256;
      int ml = i >> 4, kq = (i & 15) << 2;
      float4 v = *reinterpret_cast<const float4*>(
          &y2[(size_t)(m0 + ml) * 256 + kc + kq]);
      ys[kq + 0][ml] = v.x; ys[kq + 1][ml] = v.y;
      ys[kq + 2][ml] = v.z; ys[kq + 3][ml] = v.w;
    }
    #pragma unroll
    for (int jj = 0; jj < 8; ++jj) {
      int i = tid + jj * 256;
      int cc = i >> 4, kq = (i & 15) << 2;
      float4 v = *reinterpret_cast<const float4*>(&Wout[(size_t)cc * 256 + kc + kq]);
      ws2[kq + 0][cc] = v.x; ws2[kq + 1][cc] = v.y;
      ws2[kq + 2][cc] = v.z; ws2[kq + 3][cc] = v.w;
    }
    __syncthreads();
    for (int kk = 0; kk < 64; ++kk) {
      float4 xa = *reinterpret_cast<const float4*>(&ys[kk][tx * 8]);
      float4 xb = *reinterpret_cast<const float4*>(&ys[kk][tx * 8 + 4]);
      float4 wa = *reinterpret_cast<const float4*>(&ws2[kk][ty * 4]);
      float xv[8] = {xa.x, xa.y, xa.z, xa.w, xb.x, xb.y, xb.z, xb.w};
      float wv[4] = {wa.x, wa.y, wa.z, wa.w};
      #pragma unroll
      for (int i2 = 0; i2 < 8; ++i2)
        #pragma unroll
        for (int j2 = 0; j2 < 4; ++j2)
          acc[i2][j2] += xv[i2] * wv[j2];
    }
    __syncthreads();
  }
  #pragma unroll
  for (int j2 = 0; j2 < 4; ++j2) {
    int cc = ty * 4 + j2;
    size_t base = ((size_t)(b * 128 + cc)) * 4096 + l0 + tx * 8;
    float4 xa = *reinterpret_cast<const float4*>(&x[base]);
    float4 xb = *reinterpret_cast<const float4*>(&x[base + 4]);
    float4 r0{acc[0][j2] + xa.x, acc[1][j2] + xa.y, acc[2][j2] + xa.z, acc[3][j2] + xa.w};
    float4 r1{acc[4][j2] + xb.x, acc[5][j2] + xb.y, acc[6][j2] + xb.z, acc[7][j2] + xb.w};
    *reinterpret_cast<float4*>(&out[base]) = r0;
    *reinterpret_cast<float4*>(&out[base + 4]) = r1;
  }
}

extern "C" void kernel_launch(void* const* d_in, const int* in_sizes, int n_in,
                              void* d_out, int out_size, void* d_ws, size_t ws_size,
                              hipStream_t stream) {
  const float* x         = (const float*)d_in[0];
  const float* proj_w    = (const float*)d_in[1];
  const float* in_proj_w = (const float*)d_in[2];
  const float* conv_w    = (const float*)d_in[3];
  const float* conv_b    = (const float*)d_in[4];
  const float* x_proj_w  = (const float*)d_in[5];
  const float* dt_proj_w = (const float*)d_in[6];
  const float* dt_proj_b = (const float*)d_in[7];
  const float* A_log     = (const float*)d_in[8];
  const float* Dvec      = (const float*)d_in[9];
  const float* out_proj_w= (const float*)d_in[10];

  float* ws   = (float*)d_ws;
  float* wT   = ws;                        // 10240 f
  float* Aneg = wT + 10240;                // 4096 f
  unsigned short* W2b = (unsigned short*)(Aneg + 4096);  // 65536 u16 (32768 f)
  float* xz   = Aneg + 4096 + 32768;       // 8388608 f (32 MB)
  float* xc   = xz + 8388608;              // 4194304 f (16 MB)
  float* BC   = xc + 4194304;              // 524288 f (2 MB)
  float* dlt  = BC + 524288;               // 4194304 f (16 MB) -- also y2 (alias)
  float* Ssum = dlt + 4194304;             // 131072 f
  float* chH  = Ssum + 131072;             // 2097152 f (8 MB)
  float* chS  = chH + 2097152;             // 2097152 f (8 MB)   total ~87 MB
  float* y2   = dlt;
  float* out  = (float*)d_out;

  prep_kernel<<<312, 256, 0, stream>>>(proj_w, in_proj_w, x_proj_w, A_log, W2b, wT, Aneg);
  gemm_xz_kernel<<<256, 256, 0, stream>>>(x, W2b, xz);
  conv_silu_kernel<<<2048, 256, 0, stream>>>(xz, conv_w, conv_b, xc);
  xdbl_scan1_kernel<<<512, 256, 0, stream>>>(xc, wT, dt_proj_w, dt_proj_b, Aneg,
                                             BC, dlt, Ssum, chH);
  scan2_kernel<<<64, 256, 0, stream>>>(Aneg, Ssum, chH, chS);
  scan3_kernel<<<512, 256, 0, stream>>>(dlt, xc, BC, Aneg, chS, Dvec, xz, y2);
  gemm_out_kernel<<<256, 256, 0, stream>>>(y2, out_proj_w, x, out);
}

// Round 5
// 185.049 us; speedup vs baseline: 1.8360x; 1.1893x over previous
//
#include <hip/hip_runtime.h>

// Mamba2D: B=4, C=128, H=W=64 (L=4096), D_INNER=256, D_STATE=16, DT_RANK=8, D_CONV=4
//  prep:      W2b=bf16(in_proj@proj); wTb48=bf16 pad48(x_proj_w); Woutb=bf16(out_proj_w); Aneg
//  gemm_xz:   bf16 MFMA, xz[b,l,o]=sum_c W2[o,c]*x[b,c,l]  (fp32 out)
//  conv_silu: xc = silu(conv4(xz[:, :256]) + b)  -> fp32 xc + bf16 xcb
//  xdbl_mfma: xdbl48[m][48] = xcb @ wTb48^T   (cols 0..7 dt_r, 8..23 B, 24..39 C)
//  scan1:     per-chunk (32 steps): recompute delta in-reg, h[16] recurrence -> Ssum, chH
//  scan2:     chunk prefix -> chS
//  scan3:     replay + y, epilogue (y+xc*D)*silu(z) -> y2b (bf16)
//  gemm_out:  bf16 MFMA, out = Wout @ y2 + x

#define NCHUNK 128
#define CLEN 32

using s16x8 = __attribute__((ext_vector_type(8))) short;
using f32x4 = __attribute__((ext_vector_type(4))) float;

__device__ inline unsigned short f2bf(float f) {
  unsigned u = __float_as_uint(f);
  u = u + 0x7FFF + ((u >> 16) & 1);
  return (unsigned short)(u >> 16);
}

// ---------------- prep ----------------
__global__ void prep_kernel(const float* __restrict__ proj_w,
                            const float* __restrict__ in_proj_w,
                            const float* __restrict__ x_proj_w,
                            const float* __restrict__ out_proj_w,
                            const float* __restrict__ A_log,
                            unsigned short* __restrict__ W2b,
                            unsigned short* __restrict__ wTb48,
                            unsigned short* __restrict__ Woutb,
                            float* __restrict__ Aneg) {
  int idx = blockIdx.x * blockDim.x + threadIdx.x;
  if (idx < 65536) {
    int o = idx >> 7, c = idx & 127;
    float acc = 0.f;
    #pragma unroll 4
    for (int i = 0; i < 128; ++i)
      acc += in_proj_w[o * 128 + i] * proj_w[i * 128 + c];
    W2b[idx] = f2bf(acc);
  } else if (idx < 65536 + 12288) {
    int t = idx - 65536;
    int j = t >> 8, k = t & 255;
    wTb48[t] = (j < 40) ? f2bf(x_proj_w[j * 256 + k]) : (unsigned short)0;
  } else if (idx < 65536 + 12288 + 32768) {
    int t = idx - (65536 + 12288);
    Woutb[t] = f2bf(out_proj_w[t]);
  } else if (idx < 65536 + 12288 + 32768 + 4096) {
    int t = idx - (65536 + 12288 + 32768);
    Aneg[t] = -__expf(A_log[t]);
  }
}

// ---------------- xz GEMM via bf16 MFMA (validated layout) ----------------
__global__ __launch_bounds__(256, 1) void gemm_xz_kernel(
    const float* __restrict__ x, const unsigned short* __restrict__ W2b,
    float* __restrict__ xz) {
  __shared__ __align__(16) unsigned short At[128 * 128];
  __shared__ __align__(16) unsigned short Bt[256 * 128];
  int m0 = (blockIdx.x >> 1) * 128;
  int o0 = (blockIdx.x & 1) * 256;
  int b  = m0 >> 12;
  int l0 = m0 & 4095;
  int t = threadIdx.x;
  #pragma unroll
  for (int j = 0; j < 16; ++j) {
    int flat = t + j * 256;
    int cr = flat >> 5, lq = (flat & 31) << 2;
    float4 v = *reinterpret_cast<const float4*>(
        &x[((size_t)(b * 128 + cr)) * 4096 + l0 + lq]);
    float vv[4] = {v.x, v.y, v.z, v.w};
    #pragma unroll
    for (int e = 0; e < 4; ++e) {
      int l = lq + e;
      int g = (cr >> 3) ^ ((l & 7) << 1);
      At[l * 128 + g * 8 + (cr & 7)] = f2bf(vv[e]);
    }
  }
  #pragma unroll
  for (int j = 0; j < 16; ++j) {
    int flat = t + j * 256;
    int row = flat >> 4, gB = flat & 15;
    s16x8 v = *reinterpret_cast<const s16x8*>(&W2b[(size_t)(o0 + row) * 128 + gB * 8]);
    int g = gB ^ ((row & 7) << 1);
    *reinterpret_cast<s16x8*>(&Bt[row * 128 + g * 8]) = v;
  }
  __syncthreads();
  int ln = t & 63, wave = t >> 6;
  int wm = wave & 1, wn = wave >> 1;
  f32x4 acc[4][8] = {};
  #pragma unroll
  for (int ks = 0; ks < 4; ++ks) {
    int gk = ks * 4 + (ln >> 4);
    s16x8 a[4], bb[8];
    #pragma unroll
    for (int mi = 0; mi < 4; ++mi) {
      int lr = wm * 64 + mi * 16 + (ln & 15);
      a[mi] = *reinterpret_cast<const s16x8*>(&At[lr * 128 + (gk ^ ((lr & 7) << 1)) * 8]);
    }
    #pragma unroll
    for (int ni = 0; ni < 8; ++ni) {
      int orow = wn * 128 + ni * 16 + (ln & 15);
      bb[ni] = *reinterpret_cast<const s16x8*>(&Bt[orow * 128 + (gk ^ ((orow & 7) << 1)) * 8]);
    }
    #pragma unroll
    for (int mi = 0; mi < 4; ++mi)
      #pragma unroll
      for (int ni = 0; ni < 8; ++ni)
        acc[mi][ni] = __builtin_amdgcn_mfma_f32_16x16x32_bf16(a[mi], bb[ni], acc[mi][ni], 0, 0, 0);
  }
  #pragma unroll
  for (int mi = 0; mi < 4; ++mi)
    #pragma unroll
    for (int ni = 0; ni < 8; ++ni)
      #pragma unroll
      for (int r = 0; r < 4; ++r) {
        int row = wm * 64 + mi * 16 + (ln >> 4) * 4 + r;
        int col = wn * 128 + ni * 16 + (ln & 15);
        xz[(size_t)(m0 + row) * 512 + o0 + col] = acc[mi][ni][r];
      }
}

// ---------------- causal depthwise conv4 + silu; fp32 + bf16 outs ----------------
__global__ __launch_bounds__(256) void conv_silu_kernel(
    const float* __restrict__ xz, const float* __restrict__ conv_w,
    const float* __restrict__ conv_b, float* __restrict__ xc,
    unsigned short* __restrict__ xcb) {
  int bl0 = blockIdx.x * 8;
  int d = threadIdx.x;
  int l0 = bl0 & 4095;
  float w0 = conv_w[d * 4 + 0], w1 = conv_w[d * 4 + 1];
  float w2 = conv_w[d * 4 + 2], w3 = conv_w[d * 4 + 3];
  float cb = conv_b[d];
  float xm1 = (l0 >= 1) ? xz[(size_t)(bl0 - 1) * 512 + d] : 0.f;
  float xm2 = (l0 >= 2) ? xz[(size_t)(bl0 - 2) * 512 + d] : 0.f;
  float xm3 = (l0 >= 3) ? xz[(size_t)(bl0 - 3) * 512 + d] : 0.f;
  #pragma unroll
  for (int r = 0; r < 8; ++r) {
    size_t bl = bl0 + r;
    float x0 = xz[bl * 512 + d];
    float acc = cb + w3 * x0 + w2 * xm1 + w1 * xm2 + w0 * xm3;
    float s = acc * (1.f / (1.f + __expf(-acc)));
    xc[bl * 256 + d] = s;
    xcb[bl * 256 + d] = f2bf(s);
    xm3 = xm2; xm2 = xm1; xm1 = x0;
  }
}

// ---------------- x_dbl via bf16 MFMA: [16384 x 48] = xcb @ wTb48^T ----------------
__global__ __launch_bounds__(256) void xdbl_mfma_kernel(
    const unsigned short* __restrict__ xcb, const unsigned short* __restrict__ wTb48,
    float* __restrict__ xdbl48) {
  __shared__ __align__(16) unsigned short At[64 * 256];
  __shared__ __align__(16) unsigned short Bt[48 * 256];
  int m0 = blockIdx.x * 64;
  int t = threadIdx.x;
  #pragma unroll
  for (int it = 0; it < 8; ++it) {
    int f = t + it * 256;
    int row = f >> 5, g0 = f & 31;
    s16x8 v = *reinterpret_cast<const s16x8*>(&xcb[(size_t)(m0 + row) * 256 + g0 * 8]);
    int g = g0 ^ ((row & 7) << 1);
    *reinterpret_cast<s16x8*>(&At[row * 256 + g * 8]) = v;
  }
  #pragma unroll
  for (int it = 0; it < 6; ++it) {
    int f = t + it * 256;
    int row = f >> 5, g0 = f & 31;
    s16x8 v = *reinterpret_cast<const s16x8*>(&wTb48[(size_t)row * 256 + g0 * 8]);
    int g = g0 ^ ((row & 7) << 1);
    *reinterpret_cast<s16x8*>(&Bt[row * 256 + g * 8]) = v;
  }
  __syncthreads();
  int ln = t & 63, wm = t >> 6;
  f32x4 acc[3] = {};
  #pragma unroll
  for (int ks = 0; ks < 8; ++ks) {
    int gk = ks * 4 + (ln >> 4);
    int ar = wm * 16 + (ln & 15);
    s16x8 a = *reinterpret_cast<const s16x8*>(&At[ar * 256 + (gk ^ ((ar & 7) << 1)) * 8]);
    #pragma unroll
    for (int nt = 0; nt < 3; ++nt) {
      int br = nt * 16 + (ln & 15);
      s16x8 bb = *reinterpret_cast<const s16x8*>(&Bt[br * 256 + (gk ^ ((br & 7) << 1)) * 8]);
      acc[nt] = __builtin_amdgcn_mfma_f32_16x16x32_bf16(a, bb, acc[nt], 0, 0, 0);
    }
  }
  #pragma unroll
  for (int nt = 0; nt < 3; ++nt)
    #pragma unroll
    for (int r = 0; r < 4; ++r) {
      int row = m0 + wm * 16 + (ln >> 4) * 4 + r;
      xdbl48[(size_t)row * 48 + nt * 16 + (ln & 15)] = acc[nt][r];
    }
}

// ---------------- scan phase 1: delta in-reg + h[16] recurrence ----------------
__global__ __launch_bounds__(256) void scan1_kernel(
    const float* __restrict__ xc, const float* __restrict__ xdbl48,
    const float* __restrict__ dt_proj_w, const float* __restrict__ dt_proj_b,
    const float* __restrict__ Aneg,
    float* __restrict__ Ssum, float* __restrict__ chH) {
  __shared__ __align__(16) float lBC[CLEN][32];
  __shared__ __align__(16) float sdtr[CLEN][8];
  int bc = blockIdx.x;
  int b = bc >> 7;
  int bl0 = bc * 32;
  int tid = threadIdx.x;
  {
    int t0 = tid >> 3, q = (tid & 7) << 2;
    *reinterpret_cast<float4*>(&lBC[t0][q]) =
        *reinterpret_cast<const float4*>(&xdbl48[(size_t)(bl0 + t0) * 48 + 8 + q]);
    if (tid < 64) {
      int t1 = tid >> 1, q1 = (tid & 1) << 2;
      *reinterpret_cast<float4*>(&sdtr[t1][q1]) =
          *reinterpret_cast<const float4*>(&xdbl48[(size_t)(bl0 + t1) * 48 + q1]);
    }
  }
  int d = tid;
  float wrow[8];
  *reinterpret_cast<float4*>(&wrow[0]) =
      *reinterpret_cast<const float4*>(&dt_proj_w[d * 8]);
  *reinterpret_cast<float4*>(&wrow[4]) =
      *reinterpret_cast<const float4*>(&dt_proj_w[d * 8 + 4]);
  float bb = dt_proj_b[d];
  float An[16];
  #pragma unroll
  for (int q = 0; q < 4; ++q)
    *reinterpret_cast<float4*>(&An[q * 4]) =
        *reinterpret_cast<const float4*>(&Aneg[d * 16 + q * 4]);
  float xv[CLEN];
  #pragma unroll
  for (int t = 0; t < CLEN; ++t)
    xv[t] = xc[(size_t)(bl0 + t) * 256 + d];
  __syncthreads();
  float h[16] = {};
  float S = 0.f;
  #pragma unroll
  for (int t = 0; t < CLEN; ++t) {
    float a = bb;
    #pragma unroll
    for (int q = 0; q < 8; ++q) a += sdtr[t][q] * wrow[q];
    float dlv = fmaxf(a, 0.f) + __logf(1.f + __expf(-fabsf(a)));
    S += dlv;
    float dlx = dlv * xv[t];
    float4 B0 = *reinterpret_cast<const float4*>(&lBC[t][0]);
    float4 B1 = *reinterpret_cast<const float4*>(&lBC[t][4]);
    float4 B2 = *reinterpret_cast<const float4*>(&lBC[t][8]);
    float4 B3 = *reinterpret_cast<const float4*>(&lBC[t][12]);
    float Bv[16] = {B0.x,B0.y,B0.z,B0.w,B1.x,B1.y,B1.z,B1.w,
                    B2.x,B2.y,B2.z,B2.w,B3.x,B3.y,B3.z,B3.w};
    #pragma unroll
    for (int n = 0; n < 16; ++n)
      h[n] = __expf(dlv * An[n]) * h[n] + dlx * Bv[n];
  }
  int c = bc & 127;
  int p = b * 256 + d;
  Ssum[c * 1024 + p] = S;
  size_t base = ((size_t)(c * 1024 + p)) * 16;
  #pragma unroll
  for (int q = 0; q < 4; ++q) {
    float4 v{h[q*4+0], h[q*4+1], h[q*4+2], h[q*4+3]};
    *reinterpret_cast<float4*>(&chH[base + q * 4]) = v;
  }
}

// ---------------- scan phase 2: chunk prefix ----------------
__global__ void scan2_kernel(const float* __restrict__ Aneg,
                             const float* __restrict__ Ssum,
                             const float* __restrict__ chH,
                             float* __restrict__ chS) {
  int q = blockIdx.x * blockDim.x + threadIdx.x;  // 0..16383
  int p = q >> 4, n = q & 15;
  int d = p & 255;
  float An = Aneg[d * 16 + n];
  float h = 0.f;
  #pragma unroll 8
  for (int c = 0; c < NCHUNK; ++c) {
    size_t idx = ((size_t)(c * 1024 + p)) * 16 + n;
    float S = Ssum[c * 1024 + p];
    float hl = chH[idx];
    chS[idx] = h;
    h = __expf(An * S) * h + hl;
  }
}

// ---------------- scan phase 3: replay + y + epilogue -> bf16 y2 ----------------
__global__ __launch_bounds__(256) void scan3_kernel(
    const float* __restrict__ xc, const float* __restrict__ xdbl48,
    const float* __restrict__ dt_proj_w, const float* __restrict__ dt_proj_b,
    const float* __restrict__ Aneg, const float* __restrict__ chS,
    const float* __restrict__ Dvec, const float* __restrict__ xz,
    unsigned short* __restrict__ y2b) {
  __shared__ __align__(16) float lBC[CLEN][32];
  __shared__ __align__(16) float sdtr[CLEN][8];
  int bc = blockIdx.x;
  int b = bc >> 7, c = bc & 127;
  int bl0 = bc * 32;
  int tid = threadIdx.x;
  {
    int t0 = tid >> 3, q = (tid & 7) << 2;
    *reinterpret_cast<float4*>(&lBC[t0][q]) =
        *reinterpret_cast<const float4*>(&xdbl48[(size_t)(bl0 + t0) * 48 + 8 + q]);
    if (tid < 64) {
      int t1 = tid >> 1, q1 = (tid & 1) << 2;
      *reinterpret_cast<float4*>(&sdtr[t1][q1]) =
          *reinterpret_cast<const float4*>(&xdbl48[(size_t)(bl0 + t1) * 48 + q1]);
    }
  }
  int d = tid;
  float wrow[8];
  *reinterpret_cast<float4*>(&wrow[0]) =
      *reinterpret_cast<const float4*>(&dt_proj_w[d * 8]);
  *reinterpret_cast<float4*>(&wrow[4]) =
      *reinterpret_cast<const float4*>(&dt_proj_w[d * 8 + 4]);
  float bb = dt_proj_b[d];
  float An[16];
  #pragma unroll
  for (int q = 0; q < 4; ++q)
    *reinterpret_cast<float4*>(&An[q * 4]) =
        *reinterpret_cast<const float4*>(&Aneg[d * 16 + q * 4]);
  int p = b * 256 + d;
  float h[16];
  {
    size_t base = ((size_t)(c * 1024 + p)) * 16;
    #pragma unroll
    for (int q = 0; q < 4; ++q) {
      float4 v = *reinterpret_cast<const float4*>(&chS[base + q * 4]);
      h[q*4+0] = v.x; h[q*4+1] = v.y; h[q*4+2] = v.z; h[q*4+3] = v.w;
    }
  }
  float xv[CLEN], zv[CLEN];
  #pragma unroll
  for (int t = 0; t < CLEN; ++t) {
    xv[t] = xc[(size_t)(bl0 + t) * 256 + d];
    zv[t] = xz[(size_t)(bl0 + t) * 512 + 256 + d];
  }
  float Dd = Dvec[d];
  __syncthreads();
  #pragma unroll
  for (int t = 0; t < CLEN; ++t) {
    float a = bb;
    #pragma unroll
    for (int q = 0; q < 8; ++q) a += sdtr[t][q] * wrow[q];
    float dlv = fmaxf(a, 0.f) + __logf(1.f + __expf(-fabsf(a)));
    float xvv = xv[t];
    float dlx = dlv * xvv;
    float4 B0 = *reinterpret_cast<const float4*>(&lBC[t][0]);
    float4 B1 = *reinterpret_cast<const float4*>(&lBC[t][4]);
    float4 B2 = *reinterpret_cast<const float4*>(&lBC[t][8]);
    float4 B3 = *reinterpret_cast<const float4*>(&lBC[t][12]);
    float4 C0 = *reinterpret_cast<const float4*>(&lBC[t][16]);
    float4 C1 = *reinterpret_cast<const float4*>(&lBC[t][20]);
    float4 C2 = *reinterpret_cast<const float4*>(&lBC[t][24]);
    float4 C3 = *reinterpret_cast<const float4*>(&lBC[t][28]);
    float Bv[16] = {B0.x,B0.y,B0.z,B0.w,B1.x,B1.y,B1.z,B1.w,
                    B2.x,B2.y,B2.z,B2.w,B3.x,B3.y,B3.z,B3.w};
    float Cv[16] = {C0.x,C0.y,C0.z,C0.w,C1.x,C1.y,C1.z,C1.w,
                    C2.x,C2.y,C2.z,C2.w,C3.x,C3.y,C3.z,C3.w};
    float y = 0.f;
    #pragma unroll
    for (int n = 0; n < 16; ++n) {
      h[n] = __expf(dlv * An[n]) * h[n] + dlx * Bv[n];
      y += h[n] * Cv[n];
    }
    float z = zv[t];
    float sil = z * (1.f / (1.f + __expf(-z)));
    y2b[(size_t)(bl0 + t) * 256 + d] = f2bf((y + xvv * Dd) * sil);
  }
}

// ---------------- out GEMM via bf16 MFMA: out = Wout @ y2 + x ----------------
__global__ __launch_bounds__(256) void gemm_out_kernel(
    const unsigned short* __restrict__ y2b, const unsigned short* __restrict__ Woutb,
    const float* __restrict__ x, float* __restrict__ out) {
  __shared__ __align__(16) unsigned short At[64 * 256];
  __shared__ __align__(16) unsigned short Bt[128 * 256];
  int m0 = blockIdx.x * 64;
  int b = m0 >> 12, l0 = m0 & 4095;
  int t = threadIdx.x;
  #pragma unroll
  for (int it = 0; it < 8; ++it) {
    int f = t + it * 256;
    int row = f >> 5, g0 = f & 31;
    s16x8 v = *reinterpret_cast<const s16x8*>(&y2b[(size_t)(m0 + row) * 256 + g0 * 8]);
    int g = g0 ^ ((row & 7) << 1);
    *reinterpret_cast<s16x8*>(&At[row * 256 + g * 8]) = v;
  }
  #pragma unroll
  for (int it = 0; it < 16; ++it) {
    int f = t + it * 256;
    int row = f >> 5, g0 = f & 31;
    s16x8 v = *reinterpret_cast<const s16x8*>(&Woutb[(size_t)row * 256 + g0 * 8]);
    int g = g0 ^ ((row & 7) << 1);
    *reinterpret_cast<s16x8*>(&Bt[row * 256 + g * 8]) = v;
  }
  __syncthreads();
  int ln = t & 63, wm = t >> 6;
  f32x4 acc[8] = {};
  #pragma unroll
  for (int ks = 0; ks < 8; ++ks) {
    int gk = ks * 4 + (ln >> 4);
    int ar = wm * 16 + (ln & 15);
    s16x8 a = *reinterpret_cast<const s16x8*>(&At[ar * 256 + (gk ^ ((ar & 7) << 1)) * 8]);
    #pragma unroll
    for (int nt = 0; nt < 8; ++nt) {
      int br = nt * 16 + (ln & 15);
      s16x8 bb = *reinterpret_cast<const s16x8*>(&Bt[br * 256 + (gk ^ ((br & 7) << 1)) * 8]);
      acc[nt] = __builtin_amdgcn_mfma_f32_16x16x32_bf16(a, bb, acc[nt], 0, 0, 0);
    }
  }
  #pragma unroll
  for (int nt = 0; nt < 8; ++nt) {
    int cc = nt * 16 + (ln & 15);
    size_t base = ((size_t)(b * 128 + cc)) * 4096 + l0 + wm * 16 + ((ln >> 4) << 2);
    float4 xr = *reinterpret_cast<const float4*>(&x[base]);
    float4 o{acc[nt][0] + xr.x, acc[nt][1] + xr.y, acc[nt][2] + xr.z, acc[nt][3] + xr.w};
    *reinterpret_cast<float4*>(&out[base]) = o;
  }
}

extern "C" void kernel_launch(void* const* d_in, const int* in_sizes, int n_in,
                              void* d_out, int out_size, void* d_ws, size_t ws_size,
                              hipStream_t stream) {
  const float* x         = (const float*)d_in[0];
  const float* proj_w    = (const float*)d_in[1];
  const float* in_proj_w = (const float*)d_in[2];
  const float* conv_w    = (const float*)d_in[3];
  const float* conv_b    = (const float*)d_in[4];
  const float* x_proj_w  = (const float*)d_in[5];
  const float* dt_proj_w = (const float*)d_in[6];
  const float* dt_proj_b = (const float*)d_in[7];
  const float* A_log     = (const float*)d_in[8];
  const float* Dvec      = (const float*)d_in[9];
  const float* out_proj_w= (const float*)d_in[10];

  float* ws = (float*)d_ws;
  float*          Aneg   = ws;                                   // 4096 f
  unsigned short* W2b    = (unsigned short*)(ws + 4096);         // 65536 u16
  unsigned short* wTb48  = (unsigned short*)(ws + 36864);        // 12288 u16
  unsigned short* Woutb  = (unsigned short*)(ws + 43008);        // 32768 u16
  float*          xz     = ws + 59392;                           // 8388608 f (32 MB)
  float*          xc     = xz + 8388608;                         // 4194304 f (16 MB)
  unsigned short* xcb    = (unsigned short*)(xc + 4194304);      // 4194304 u16 (8 MB)
  float*          xdbl48 = xc + 4194304 + 2097152;               // 786432 f (3 MB)
  float*          Ssum   = xdbl48 + 786432;                      // 131072 f
  float*          chH    = Ssum + 131072;                        // 2097152 f (8 MB)
  float*          chS    = chH + 2097152;                        // 2097152 f (8 MB)
  unsigned short* y2b    = (unsigned short*)(chS + 2097152);     // 4194304 u16 (8 MB)
  float* out = (float*)d_out;                                    // total ~88 MB

  prep_kernel<<<448, 256, 0, stream>>>(proj_w, in_proj_w, x_proj_w, out_proj_w, A_log,
                                       W2b, wTb48, Woutb, Aneg);
  gemm_xz_kernel<<<256, 256, 0, stream>>>(x, W2b, xz);
  conv_silu_kernel<<<2048, 256, 0, stream>>>(xz, conv_w, conv_b, xc, xcb);
  xdbl_mfma_kernel<<<256, 256, 0, stream>>>(xcb, wTb48, xdbl48);
  scan1_kernel<<<512, 256, 0, stream>>>(xc, xdbl48, dt_proj_w, dt_proj_b, Aneg, Ssum, chH);
  scan2_kernel<<<64, 256, 0, stream>>>(Aneg, Ssum, chH, chS);
  scan3_kernel<<<512, 256, 0, stream>>>(xc, xdbl48, dt_proj_w, dt_proj_b, Aneg, chS,
                                        Dvec, xz, y2b);
  gemm_out_kernel<<<256, 256, 0, stream>>>(y2b, Woutb, x, out);
}

// Round 6
// 181.328 us; speedup vs baseline: 1.8737x; 1.0205x over previous
//
#include <hip/hip_runtime.h>

// Mamba2D: B=4, C=128, H=W=64 (L=4096), D_INNER=256, D_STATE=16, DT_RANK=8, D_CONV=4
//  prep:      W2b=bf16(in_proj@proj); wTb48=bf16 pad48(x_proj_w); Woutb=bf16(out_proj_w); Aneg
//  gemm_xz:   bf16 MFMA, xz[b,l,o]=sum_c W2[o,c]*x[b,c,l]  (fp32 out)
//  conv_silu: xc = silu(conv4(xz[:, :256]) + b)  -> fp32 xc + bf16 xcb
//  xdbl_mfma: xdbl48[m][48] = xcb @ wTb48^T   (cols 0..7 dt_r, 8..23 B, 24..39 C)
//  scan:      3-phase, CLEN=16 (1024 blocks -> 4 blocks/CU for occupancy),
//             chunk states chH/chS stored bf16 (keeps ws ~88MB)
//  gemm_out:  bf16 MFMA, out = Wout @ y2 + x

#define NCHUNK 256
#define CLEN 16

using s16x8 = __attribute__((ext_vector_type(8))) short;
using f32x4 = __attribute__((ext_vector_type(4))) float;

__device__ inline unsigned short f2bf(float f) {
  unsigned u = __float_as_uint(f);
  u = u + 0x7FFF + ((u >> 16) & 1);
  return (unsigned short)(u >> 16);
}
__device__ inline float bf2f_lo(unsigned v) { return __uint_as_float(v << 16); }
__device__ inline float bf2f_hi(unsigned v) { return __uint_as_float(v & 0xFFFF0000u); }

// ---------------- prep ----------------
__global__ void prep_kernel(const float* __restrict__ proj_w,
                            const float* __restrict__ in_proj_w,
                            const float* __restrict__ x_proj_w,
                            const float* __restrict__ out_proj_w,
                            const float* __restrict__ A_log,
                            unsigned short* __restrict__ W2b,
                            unsigned short* __restrict__ wTb48,
                            unsigned short* __restrict__ Woutb,
                            float* __restrict__ Aneg) {
  int idx = blockIdx.x * blockDim.x + threadIdx.x;
  if (idx < 65536) {
    int o = idx >> 7, c = idx & 127;
    float acc = 0.f;
    #pragma unroll 4
    for (int i = 0; i < 128; ++i)
      acc += in_proj_w[o * 128 + i] * proj_w[i * 128 + c];
    W2b[idx] = f2bf(acc);
  } else if (idx < 65536 + 12288) {
    int t = idx - 65536;
    int j = t >> 8, k = t & 255;
    wTb48[t] = (j < 40) ? f2bf(x_proj_w[j * 256 + k]) : (unsigned short)0;
  } else if (idx < 65536 + 12288 + 32768) {
    int t = idx - (65536 + 12288);
    Woutb[t] = f2bf(out_proj_w[t]);
  } else if (idx < 65536 + 12288 + 32768 + 4096) {
    int t = idx - (65536 + 12288 + 32768);
    Aneg[t] = -__expf(A_log[t]);
  }
}

// ---------------- xz GEMM via bf16 MFMA (validated layout) ----------------
__global__ __launch_bounds__(256, 1) void gemm_xz_kernel(
    const float* __restrict__ x, const unsigned short* __restrict__ W2b,
    float* __restrict__ xz) {
  __shared__ __align__(16) unsigned short At[128 * 128];
  __shared__ __align__(16) unsigned short Bt[256 * 128];
  int m0 = (blockIdx.x >> 1) * 128;
  int o0 = (blockIdx.x & 1) * 256;
  int b  = m0 >> 12;
  int l0 = m0 & 4095;
  int t = threadIdx.x;
  #pragma unroll
  for (int j = 0; j < 16; ++j) {
    int flat = t + j * 256;
    int cr = flat >> 5, lq = (flat & 31) << 2;
    float4 v = *reinterpret_cast<const float4*>(
        &x[((size_t)(b * 128 + cr)) * 4096 + l0 + lq]);
    float vv[4] = {v.x, v.y, v.z, v.w};
    #pragma unroll
    for (int e = 0; e < 4; ++e) {
      int l = lq + e;
      int g = (cr >> 3) ^ ((l & 7) << 1);
      At[l * 128 + g * 8 + (cr & 7)] = f2bf(vv[e]);
    }
  }
  #pragma unroll
  for (int j = 0; j < 16; ++j) {
    int flat = t + j * 256;
    int row = flat >> 4, gB = flat & 15;
    s16x8 v = *reinterpret_cast<const s16x8*>(&W2b[(size_t)(o0 + row) * 128 + gB * 8]);
    int g = gB ^ ((row & 7) << 1);
    *reinterpret_cast<s16x8*>(&Bt[row * 128 + g * 8]) = v;
  }
  __syncthreads();
  int ln = t & 63, wave = t >> 6;
  int wm = wave & 1, wn = wave >> 1;
  f32x4 acc[4][8] = {};
  #pragma unroll
  for (int ks = 0; ks < 4; ++ks) {
    int gk = ks * 4 + (ln >> 4);
    s16x8 a[4], bb[8];
    #pragma unroll
    for (int mi = 0; mi < 4; ++mi) {
      int lr = wm * 64 + mi * 16 + (ln & 15);
      a[mi] = *reinterpret_cast<const s16x8*>(&At[lr * 128 + (gk ^ ((lr & 7) << 1)) * 8]);
    }
    #pragma unroll
    for (int ni = 0; ni < 8; ++ni) {
      int orow = wn * 128 + ni * 16 + (ln & 15);
      bb[ni] = *reinterpret_cast<const s16x8*>(&Bt[orow * 128 + (gk ^ ((orow & 7) << 1)) * 8]);
    }
    #pragma unroll
    for (int mi = 0; mi < 4; ++mi)
      #pragma unroll
      for (int ni = 0; ni < 8; ++ni)
        acc[mi][ni] = __builtin_amdgcn_mfma_f32_16x16x32_bf16(a[mi], bb[ni], acc[mi][ni], 0, 0, 0);
  }
  #pragma unroll
  for (int mi = 0; mi < 4; ++mi)
    #pragma unroll
    for (int ni = 0; ni < 8; ++ni)
      #pragma unroll
      for (int r = 0; r < 4; ++r) {
        int row = wm * 64 + mi * 16 + (ln >> 4) * 4 + r;
        int col = wn * 128 + ni * 16 + (ln & 15);
        xz[(size_t)(m0 + row) * 512 + o0 + col] = acc[mi][ni][r];
      }
}

// ---------------- causal depthwise conv4 + silu; fp32 + bf16 outs ----------------
__global__ __launch_bounds__(256) void conv_silu_kernel(
    const float* __restrict__ xz, const float* __restrict__ conv_w,
    const float* __restrict__ conv_b, float* __restrict__ xc,
    unsigned short* __restrict__ xcb) {
  int bl0 = blockIdx.x * 8;
  int d = threadIdx.x;
  int l0 = bl0 & 4095;
  float w0 = conv_w[d * 4 + 0], w1 = conv_w[d * 4 + 1];
  float w2 = conv_w[d * 4 + 2], w3 = conv_w[d * 4 + 3];
  float cb = conv_b[d];
  float xm1 = (l0 >= 1) ? xz[(size_t)(bl0 - 1) * 512 + d] : 0.f;
  float xm2 = (l0 >= 2) ? xz[(size_t)(bl0 - 2) * 512 + d] : 0.f;
  float xm3 = (l0 >= 3) ? xz[(size_t)(bl0 - 3) * 512 + d] : 0.f;
  #pragma unroll
  for (int r = 0; r < 8; ++r) {
    size_t bl = bl0 + r;
    float x0 = xz[bl * 512 + d];
    float acc = cb + w3 * x0 + w2 * xm1 + w1 * xm2 + w0 * xm3;
    float s = acc * (1.f / (1.f + __expf(-acc)));
    xc[bl * 256 + d] = s;
    xcb[bl * 256 + d] = f2bf(s);
    xm3 = xm2; xm2 = xm1; xm1 = x0;
  }
}

// ---------------- x_dbl via bf16 MFMA: [16384 x 48] = xcb @ wTb48^T ----------------
__global__ __launch_bounds__(256) void xdbl_mfma_kernel(
    const unsigned short* __restrict__ xcb, const unsigned short* __restrict__ wTb48,
    float* __restrict__ xdbl48) {
  __shared__ __align__(16) unsigned short At[64 * 256];
  __shared__ __align__(16) unsigned short Bt[48 * 256];
  int m0 = blockIdx.x * 64;
  int t = threadIdx.x;
  #pragma unroll
  for (int it = 0; it < 8; ++it) {
    int f = t + it * 256;
    int row = f >> 5, g0 = f & 31;
    s16x8 v = *reinterpret_cast<const s16x8*>(&xcb[(size_t)(m0 + row) * 256 + g0 * 8]);
    int g = g0 ^ ((row & 7) << 1);
    *reinterpret_cast<s16x8*>(&At[row * 256 + g * 8]) = v;
  }
  #pragma unroll
  for (int it = 0; it < 6; ++it) {
    int f = t + it * 256;
    int row = f >> 5, g0 = f & 31;
    s16x8 v = *reinterpret_cast<const s16x8*>(&wTb48[(size_t)row * 256 + g0 * 8]);
    int g = g0 ^ ((row & 7) << 1);
    *reinterpret_cast<s16x8*>(&Bt[row * 256 + g * 8]) = v;
  }
  __syncthreads();
  int ln = t & 63, wm = t >> 6;
  f32x4 acc[3] = {};
  #pragma unroll
  for (int ks = 0; ks < 8; ++ks) {
    int gk = ks * 4 + (ln >> 4);
    int ar = wm * 16 + (ln & 15);
    s16x8 a = *reinterpret_cast<const s16x8*>(&At[ar * 256 + (gk ^ ((ar & 7) << 1)) * 8]);
    #pragma unroll
    for (int nt = 0; nt < 3; ++nt) {
      int br = nt * 16 + (ln & 15);
      s16x8 bb = *reinterpret_cast<const s16x8*>(&Bt[br * 256 + (gk ^ ((br & 7) << 1)) * 8]);
      acc[nt] = __builtin_amdgcn_mfma_f32_16x16x32_bf16(a, bb, acc[nt], 0, 0, 0);
    }
  }
  #pragma unroll
  for (int nt = 0; nt < 3; ++nt)
    #pragma unroll
    for (int r = 0; r < 4; ++r) {
      int row = m0 + wm * 16 + (ln >> 4) * 4 + r;
      xdbl48[(size_t)row * 48 + nt * 16 + (ln & 15)] = acc[nt][r];
    }
}

// ---------------- scan phase 1: delta in-reg + h[16] recurrence (CLEN=16) ----------------
__global__ __launch_bounds__(256) void scan1_kernel(
    const float* __restrict__ xc, const float* __restrict__ xdbl48,
    const float* __restrict__ dt_proj_w, const float* __restrict__ dt_proj_b,
    const float* __restrict__ Aneg,
    float* __restrict__ Ssum, unsigned* __restrict__ chHb) {
  __shared__ __align__(16) float lBC[CLEN][32];
  __shared__ __align__(16) float sdtr[CLEN][8];
  int bc = blockIdx.x;              // 0..1023 = b*256 + c
  int b = bc >> 8, c = bc & 255;
  int bl0 = bc * CLEN;
  int tid = threadIdx.x;
  if (tid < 128) {                   // 16 rows x 32 cols of B/C
    int t0 = tid >> 3, q = (tid & 7) << 2;
    *reinterpret_cast<float4*>(&lBC[t0][q]) =
        *reinterpret_cast<const float4*>(&xdbl48[(size_t)(bl0 + t0) * 48 + 8 + q]);
  }
  if (tid < 32) {                    // 16 rows x 8 cols of dt_r
    int t1 = tid >> 1, q1 = (tid & 1) << 2;
    *reinterpret_cast<float4*>(&sdtr[t1][q1]) =
        *reinterpret_cast<const float4*>(&xdbl48[(size_t)(bl0 + t1) * 48 + q1]);
  }
  int d = tid;
  float wrow[8];
  *reinterpret_cast<float4*>(&wrow[0]) =
      *reinterpret_cast<const float4*>(&dt_proj_w[d * 8]);
  *reinterpret_cast<float4*>(&wrow[4]) =
      *reinterpret_cast<const float4*>(&dt_proj_w[d * 8 + 4]);
  float bb = dt_proj_b[d];
  float An[16];
  #pragma unroll
  for (int q = 0; q < 4; ++q)
    *reinterpret_cast<float4*>(&An[q * 4]) =
        *reinterpret_cast<const float4*>(&Aneg[d * 16 + q * 4]);
  float xv[CLEN];
  #pragma unroll
  for (int t = 0; t < CLEN; ++t)
    xv[t] = xc[(size_t)(bl0 + t) * 256 + d];
  __syncthreads();
  float h[16] = {};
  float S = 0.f;
  #pragma unroll
  for (int t = 0; t < CLEN; ++t) {
    float a = bb;
    #pragma unroll
    for (int q = 0; q < 8; ++q) a += sdtr[t][q] * wrow[q];
    float dlv = fmaxf(a, 0.f) + __logf(1.f + __expf(-fabsf(a)));
    S += dlv;
    float dlx = dlv * xv[t];
    float4 B0 = *reinterpret_cast<const float4*>(&lBC[t][0]);
    float4 B1 = *reinterpret_cast<const float4*>(&lBC[t][4]);
    float4 B2 = *reinterpret_cast<const float4*>(&lBC[t][8]);
    float4 B3 = *reinterpret_cast<const float4*>(&lBC[t][12]);
    float Bv[16] = {B0.x,B0.y,B0.z,B0.w,B1.x,B1.y,B1.z,B1.w,
                    B2.x,B2.y,B2.z,B2.w,B3.x,B3.y,B3.z,B3.w};
    #pragma unroll
    for (int n = 0; n < 16; ++n)
      h[n] = __expf(dlv * An[n]) * h[n] + dlx * Bv[n];
  }
  int p = b * 256 + d;
  Ssum[c * 1024 + p] = S;
  // pack h[16] -> 8 uints (bf16 pairs), 2x uint4 store
  unsigned up[8];
  #pragma unroll
  for (int q = 0; q < 8; ++q)
    up[q] = (unsigned)f2bf(h[2 * q]) | ((unsigned)f2bf(h[2 * q + 1]) << 16);
  size_t ub = ((size_t)(c * 1024 + p)) * 8;
  *reinterpret_cast<uint4*>(&chHb[ub])     = uint4{up[0], up[1], up[2], up[3]};
  *reinterpret_cast<uint4*>(&chHb[ub + 4]) = uint4{up[4], up[5], up[6], up[7]};
}

// ---------------- scan phase 2: chunk prefix over 256 chunks (bf16 states) ----------------
__global__ void scan2_kernel(const float* __restrict__ Aneg,
                             const float* __restrict__ Ssum,
                             const unsigned short* __restrict__ chHb,
                             unsigned short* __restrict__ chSb) {
  int q = blockIdx.x * blockDim.x + threadIdx.x;  // 0..16383
  int p = q >> 4, n = q & 15;
  int d = p & 255;
  float An = Aneg[d * 16 + n];
  float h = 0.f;
  #pragma unroll 8
  for (int c = 0; c < NCHUNK; ++c) {
    size_t idx = ((size_t)(c * 1024 + p)) * 16 + n;
    float S = Ssum[c * 1024 + p];
    float hl = bf2f_lo((unsigned)chHb[idx]);
    chSb[idx] = f2bf(h);
    h = __expf(An * S) * h + hl;
  }
}

// ---------------- scan phase 3: replay + y + epilogue -> bf16 y2 (CLEN=16) ----------------
__global__ __launch_bounds__(256) void scan3_kernel(
    const float* __restrict__ xc, const float* __restrict__ xdbl48,
    const float* __restrict__ dt_proj_w, const float* __restrict__ dt_proj_b,
    const float* __restrict__ Aneg, const unsigned* __restrict__ chSb,
    const float* __restrict__ Dvec, const float* __restrict__ xz,
    unsigned short* __restrict__ y2b) {
  __shared__ __align__(16) float lBC[CLEN][32];
  __shared__ __align__(16) float sdtr[CLEN][8];
  int bc = blockIdx.x;
  int b = bc >> 8, c = bc & 255;
  int bl0 = bc * CLEN;
  int tid = threadIdx.x;
  if (tid < 128) {
    int t0 = tid >> 3, q = (tid & 7) << 2;
    *reinterpret_cast<float4*>(&lBC[t0][q]) =
        *reinterpret_cast<const float4*>(&xdbl48[(size_t)(bl0 + t0) * 48 + 8 + q]);
  }
  if (tid < 32) {
    int t1 = tid >> 1, q1 = (tid & 1) << 2;
    *reinterpret_cast<float4*>(&sdtr[t1][q1]) =
        *reinterpret_cast<const float4*>(&xdbl48[(size_t)(bl0 + t1) * 48 + q1]);
  }
  int d = tid;
  float wrow[8];
  *reinterpret_cast<float4*>(&wrow[0]) =
      *reinterpret_cast<const float4*>(&dt_proj_w[d * 8]);
  *reinterpret_cast<float4*>(&wrow[4]) =
      *reinterpret_cast<const float4*>(&dt_proj_w[d * 8 + 4]);
  float bb = dt_proj_b[d];
  float An[16];
  #pragma unroll
  for (int q = 0; q < 4; ++q)
    *reinterpret_cast<float4*>(&An[q * 4]) =
        *reinterpret_cast<const float4*>(&Aneg[d * 16 + q * 4]);
  int p = b * 256 + d;
  float h[16];
  {
    size_t ub = ((size_t)(c * 1024 + p)) * 8;
    uint4 s0 = *reinterpret_cast<const uint4*>(&chSb[ub]);
    uint4 s1 = *reinterpret_cast<const uint4*>(&chSb[ub + 4]);
    h[0] = bf2f_lo(s0.x); h[1] = bf2f_hi(s0.x);
    h[2] = bf2f_lo(s0.y); h[3] = bf2f_hi(s0.y);
    h[4] = bf2f_lo(s0.z); h[5] = bf2f_hi(s0.z);
    h[6] = bf2f_lo(s0.w); h[7] = bf2f_hi(s0.w);
    h[8] = bf2f_lo(s1.x); h[9] = bf2f_hi(s1.x);
    h[10] = bf2f_lo(s1.y); h[11] = bf2f_hi(s1.y);
    h[12] = bf2f_lo(s1.z); h[13] = bf2f_hi(s1.z);
    h[14] = bf2f_lo(s1.w); h[15] = bf2f_hi(s1.w);
  }
  float xv[CLEN], zv[CLEN];
  #pragma unroll
  for (int t = 0; t < CLEN; ++t) {
    xv[t] = xc[(size_t)(bl0 + t) * 256 + d];
    zv[t] = xz[(size_t)(bl0 + t) * 512 + 256 + d];
  }
  float Dd = Dvec[d];
  __syncthreads();
  #pragma unroll
  for (int t = 0; t < CLEN; ++t) {
    float a = bb;
    #pragma unroll
    for (int q = 0; q < 8; ++q) a += sdtr[t][q] * wrow[q];
    float dlv = fmaxf(a, 0.f) + __logf(1.f + __expf(-fabsf(a)));
    float xvv = xv[t];
    float dlx = dlv * xvv;
    float4 B0 = *reinterpret_cast<const float4*>(&lBC[t][0]);
    float4 B1 = *reinterpret_cast<const float4*>(&lBC[t][4]);
    float4 B2 = *reinterpret_cast<const float4*>(&lBC[t][8]);
    float4 B3 = *reinterpret_cast<const float4*>(&lBC[t][12]);
    float4 C0 = *reinterpret_cast<const float4*>(&lBC[t][16]);
    float4 C1 = *reinterpret_cast<const float4*>(&lBC[t][20]);
    float4 C2 = *reinterpret_cast<const float4*>(&lBC[t][24]);
    float4 C3 = *reinterpret_cast<const float4*>(&lBC[t][28]);
    float Bv[16] = {B0.x,B0.y,B0.z,B0.w,B1.x,B1.y,B1.z,B1.w,
                    B2.x,B2.y,B2.z,B2.w,B3.x,B3.y,B3.z,B3.w};
    float Cv[16] = {C0.x,C0.y,C0.z,C0.w,C1.x,C1.y,C1.z,C1.w,
                    C2.x,C2.y,C2.z,C2.w,C3.x,C3.y,C3.z,C3.w};
    float y = 0.f;
    #pragma unroll
    for (int n = 0; n < 16; ++n) {
      h[n] = __expf(dlv * An[n]) * h[n] + dlx * Bv[n];
      y += h[n] * Cv[n];
    }
    float z = zv[t];
    float sil = z * (1.f / (1.f + __expf(-z)));
    y2b[(size_t)(bl0 + t) * 256 + d] = f2bf((y + xvv * Dd) * sil);
  }
}

// ---------------- out GEMM via bf16 MFMA: out = Wout @ y2 + x ----------------
__global__ __launch_bounds__(256) void gemm_out_kernel(
    const unsigned short* __restrict__ y2b, const unsigned short* __restrict__ Woutb,
    const float* __restrict__ x, float* __restrict__ out) {
  __shared__ __align__(16) unsigned short At[64 * 256];
  __shared__ __align__(16) unsigned short Bt[128 * 256];
  int m0 = blockIdx.x * 64;
  int b = m0 >> 12, l0 = m0 & 4095;
  int t = threadIdx.x;
  #pragma unroll
  for (int it = 0; it < 8; ++it) {
    int f = t + it * 256;
    int row = f >> 5, g0 = f & 31;
    s16x8 v = *reinterpret_cast<const s16x8*>(&y2b[(size_t)(m0 + row) * 256 + g0 * 8]);
    int g = g0 ^ ((row & 7) << 1);
    *reinterpret_cast<s16x8*>(&At[row * 256 + g * 8]) = v;
  }
  #pragma unroll
  for (int it = 0; it < 16; ++it) {
    int f = t + it * 256;
    int row = f >> 5, g0 = f & 31;
    s16x8 v = *reinterpret_cast<const s16x8*>(&Woutb[(size_t)row * 256 + g0 * 8]);
    int g = g0 ^ ((row & 7) << 1);
    *reinterpret_cast<s16x8*>(&Bt[row * 256 + g * 8]) = v;
  }
  __syncthreads();
  int ln = t & 63, wm = t >> 6;
  f32x4 acc[8] = {};
  #pragma unroll
  for (int ks = 0; ks < 8; ++ks) {
    int gk = ks * 4 + (ln >> 4);
    int ar = wm * 16 + (ln & 15);
    s16x8 a = *reinterpret_cast<const s16x8*>(&At[ar * 256 + (gk ^ ((ar & 7) << 1)) * 8]);
    #pragma unroll
    for (int nt = 0; nt < 8; ++nt) {
      int br = nt * 16 + (ln & 15);
      s16x8 bb = *reinterpret_cast<const s16x8*>(&Bt[br * 256 + (gk ^ ((br & 7) << 1)) * 8]);
      acc[nt] = __builtin_amdgcn_mfma_f32_16x16x32_bf16(a, bb, acc[nt], 0, 0, 0);
    }
  }
  #pragma unroll
  for (int nt = 0; nt < 8; ++nt) {
    int cc = nt * 16 + (ln & 15);
    size_t base = ((size_t)(b * 128 + cc)) * 4096 + l0 + wm * 16 + ((ln >> 4) << 2);
    float4 xr = *reinterpret_cast<const float4*>(&x[base]);
    float4 o{acc[nt][0] + xr.x, acc[nt][1] + xr.y, acc[nt][2] + xr.z, acc[nt][3] + xr.w};
    *reinterpret_cast<float4*>(&out[base]) = o;
  }
}

extern "C" void kernel_launch(void* const* d_in, const int* in_sizes, int n_in,
                              void* d_out, int out_size, void* d_ws, size_t ws_size,
                              hipStream_t stream) {
  const float* x         = (const float*)d_in[0];
  const float* proj_w    = (const float*)d_in[1];
  const float* in_proj_w = (const float*)d_in[2];
  const float* conv_w    = (const float*)d_in[3];
  const float* conv_b    = (const float*)d_in[4];
  const float* x_proj_w  = (const float*)d_in[5];
  const float* dt_proj_w = (const float*)d_in[6];
  const float* dt_proj_b = (const float*)d_in[7];
  const float* A_log     = (const float*)d_in[8];
  const float* Dvec      = (const float*)d_in[9];
  const float* out_proj_w= (const float*)d_in[10];

  float* ws = (float*)d_ws;
  float*          Aneg   = ws;                                   // 4096 f
  unsigned short* W2b    = (unsigned short*)(ws + 4096);         // 65536 u16
  unsigned short* wTb48  = (unsigned short*)(ws + 36864);        // 12288 u16
  unsigned short* Woutb  = (unsigned short*)(ws + 43008);        // 32768 u16
  float*          xz     = ws + 59392;                           // 8388608 f (32 MB)
  float*          xc     = xz + 8388608;                         // 4194304 f (16 MB)
  unsigned short* xcb    = (unsigned short*)(xc + 4194304);      // 4194304 u16 (8 MB)
  float*          xdbl48 = xc + 4194304 + 2097152;               // 786432 f (3 MB)
  float*          Ssum   = xdbl48 + 786432;                      // 262144 f (1 MB)
  unsigned*       chHb   = (unsigned*)(Ssum + 262144);           // 256*1024*16 u16 = 8 MB
  unsigned*       chSb   = chHb + 2097152;                       // 8 MB
  unsigned short* y2b    = (unsigned short*)(chSb + 2097152);    // 4194304 u16 (8 MB)
  float* out = (float*)d_out;                                    // total ~89 MB

  prep_kernel<<<448, 256, 0, stream>>>(proj_w, in_proj_w, x_proj_w, out_proj_w, A_log,
                                       W2b, wTb48, Woutb, Aneg);
  gemm_xz_kernel<<<256, 256, 0, stream>>>(x, W2b, xz);
  conv_silu_kernel<<<2048, 256, 0, stream>>>(xz, conv_w, conv_b, xc, xcb);
  xdbl_mfma_kernel<<<256, 256, 0, stream>>>(xcb, wTb48, xdbl48);
  scan1_kernel<<<1024, 256, 0, stream>>>(xc, xdbl48, dt_proj_w, dt_proj_b, Aneg,
                                         Ssum, chHb);
  scan2_kernel<<<64, 256, 0, stream>>>(Aneg, Ssum, (const unsigned short*)chHb,
                                       (unsigned short*)chSb);
  scan3_kernel<<<1024, 256, 0, stream>>>(xc, xdbl48, dt_proj_w, dt_proj_b, Aneg,
                                         chSb, Dvec, xz, y2b);
  gemm_out_kernel<<<256, 256, 0, stream>>>(y2b, Woutb, x, out);
}